// Round 10
// baseline (613.007 us; speedup 1.0000x reference)
//
#include <hip/hip_runtime.h>
#include <hip/hip_bf16.h>

#define NSAMP 131072
#define TA    90
#define HID   128
#define DLAT  512

// d_out layout (float elements): quant[N*512], code[N*4], recon[N*90], loss[1]
#define OFF_CODE  67108864ll
#define OFF_RECON (67108864ll + 524288ll)
#define OFF_LOSS  (67108864ll + 524288ll + 11796480ll)

// k_encvq LDS (floats): Act[128][68]=8704 | Wl 2x[16][128]=4096 | PZ[4][64]=256
// Act region overlays (post-GEMM): zdot[64][129] (0..8255) | flags[64] ints
// (8256..8319) | h1tmp[128] (8320..8447) | h2tmp[128] (8448..8575)
#define ACT_ST 68
#define WLF    8704
#define PZF    12800
#define SHF    13056
#define FLGF   8256
#define H1TF   8320
#define H2TF   8448

typedef __attribute__((ext_vector_type(8))) short bf16x8;
typedef __attribute__((ext_vector_type(4))) short s16x4;
typedef __attribute__((ext_vector_type(4))) float f32x4;
typedef unsigned short ushort_t;
#define MFMA16(a, b, c) __builtin_amdgcn_mfma_f32_16x16x32_bf16(a, b, c, 0, 0, 0)

__device__ __forceinline__ ushort_t f2bf(float f) {
    unsigned u = __float_as_uint(f);
    u = (u + 0x7FFF + ((u >> 16) & 1)) >> 16;     // RNE
    return (ushort_t)u;
}
__device__ __forceinline__ float bf2f(ushort_t u) {
    return __uint_as_float(((unsigned)u) << 16);
}

__device__ __forceinline__ float dot512(const float* __restrict__ a,
                                        const float* __restrict__ b) {
    float s = 0.f;
    for (int i = 0; i < 128; ++i) {
        float4 x = ((const float4*)a)[i], y = ((const float4*)b)[i];
        s += x.x * y.x + x.y * y.y + x.z * y.z + x.w * y.w;
    }
    return s;
}

// ---- R9-verbatim 8x4 tile FMA ----
__device__ __forceinline__ void fma_tile(float (&acc)[8][4],
                                         const float* __restrict__ wl,
                                         const float* __restrict__ al) {
    float4 av = *(const float4*)al;
    float4 w0 = *(const float4*)wl;
    float4 w1 = *(const float4*)(wl + 4);
    float aa[4] = {av.x, av.y, av.z, av.w};
    float ww[8] = {w0.x, w0.y, w0.z, w0.w, w1.x, w1.y, w1.z, w1.w};
#pragma unroll
    for (int a = 0; a < 8; ++a)
#pragma unroll
        for (int b = 0; b < 4; ++b) acc[a][b] = fmaf(ww[a], aa[b], acc[a][b]);
}

// ---- R9-verbatim double-buffered GEMM engine ----
__device__ __forceinline__ void gemm_dbuf(const float* __restrict__ w, int wstride,
                                          int inRows, int nch,
                                          const float* __restrict__ Act,
                                          float* __restrict__ Wl,
                                          float (&acc)[8][4],
                                          int t, int o0, int s0) {
    const int wr = t >> 4;
    const int wc = (t & 15) * 8;
    float4 c0, c1;
    {
        int r = wr < inRows ? wr : inRows - 1;
        const float* p = w + (size_t)r * wstride + wc;
        c0 = *(const float4*)p; c1 = *(const float4*)(p + 4);
    }
    *(float4*)&Wl[wr * 128 + wc] = c0;
    *(float4*)&Wl[wr * 128 + wc + 4] = c1;
    __syncthreads();
    for (int ch = 0; ch < nch; ++ch) {
        const float* Wc = &Wl[(ch & 1) * 2048];
        const bool more = (ch + 1 < nch);
        if (more) {
            int rr = (ch + 1) * 16 + wr;
            int r = rr < inRows ? rr : inRows - 1;
            const float* p = w + (size_t)r * wstride + wc;
            c0 = *(const float4*)p; c1 = *(const float4*)(p + 4);
        }
        const float* Ab = Act + (ch * 16) * ACT_ST + s0;
#pragma unroll
        for (int j = 0; j < 16; ++j)
            fma_tile(acc, &Wc[j * 128 + o0], Ab + j * ACT_ST);
        __syncthreads();
        if (more) {
            float* Wn = &Wl[((ch + 1) & 1) * 2048];
            *(float4*)&Wn[wr * 128 + wc] = c0;
            *(float4*)&Wn[wr * 128 + wc + 4] = c1;
            __syncthreads();
        }
    }
}

// ---------------------------------------------------------------------------
// K0: precompute tables. Adds tbl6: Mhi/Mlo bf16 split of M^T ([c][j]).
// ---------------------------------------------------------------------------
__global__ void k_prep(const float* __restrict__ cb, const float* __restrict__ w3,
                       const float* __restrict__ b3, const float* __restrict__ w1d,
                       const float* __restrict__ w2d, const float* __restrict__ w3d,
                       float* __restrict__ P, float* __restrict__ M,
                       float* __restrict__ t0, float* __restrict__ v,
                       float* __restrict__ csc, float* __restrict__ cbW,
                       ushort_t* __restrict__ Qbf, ushort_t* __restrict__ w2bf,
                       ushort_t* __restrict__ w3bf,
                       ushort_t* __restrict__ Mhibf, ushort_t* __restrict__ Mlobf) {
    int tbl = blockIdx.x >> 6;
    int gid = (blockIdx.x & 63) * 256 + threadIdx.x;   // 0..16383
    int i = gid >> 7, j = gid & 127;
    if (tbl == 0) {
        P[gid] = dot512(cb + (size_t)i * 512, cb + (size_t)j * 512);
        if (gid < 128) t0[gid] = dot512(cb + (size_t)gid * 512, b3);
        if (gid == 0) csc[0] = dot512(b3, b3);
    } else if (tbl == 1) {
        M[gid] = dot512(w3 + (size_t)i * 512, cb + (size_t)j * 512);
    } else if (tbl == 2) {
        Qbf[gid] = f2bf(dot512(w3 + (size_t)i * 512, w3 + (size_t)j * 512));
        if (gid < 128) v[gid] = dot512(w3 + (size_t)gid * 512, b3);
    } else if (tbl == 3) {
        float s = 0.f;
        for (int d = 0; d < 512; ++d) s = fmaf(cb[(size_t)i * 512 + d], w1d[d * 128 + j], s);
        cbW[gid] = s;
    } else if (tbl == 4) {
        w2bf[gid] = f2bf(w2d[j * 128 + i]);            // [o][j] = w2[j][o]
    } else if (tbl == 5) {
        if (gid < 96 * 128)
            w3bf[gid] = (i < 90) ? f2bf(w3d[j * TA + i]) : (ushort_t)0;
    } else {
        // tbl6: i = code c, j = hidden j. M^T split: hi + lo bf16.
        float d = dot512(w3 + (size_t)j * 512, cb + (size_t)i * 512);
        ushort_t hi = f2bf(d);
        Mhibf[gid] = hi;
        Mlobf[gid] = f2bf(d - bf2f(hi));
    }
}

// ---------------------------------------------------------------------------
// K1: encoder (L1,L2 fp32) + merged MFMA phase (Q-loss + M-scoring split-bf16)
//     + argmin with margin-gated exact fallback. LDS 52.2 KB -> 3 blocks/CU.
// ---------------------------------------------------------------------------
__launch_bounds__(256, 3)
__global__ void k_encvq(const float* __restrict__ X,
                        const float* __restrict__ w1, const float* __restrict__ b1,
                        const float* __restrict__ w2, const float* __restrict__ b2,
                        const float* __restrict__ Mt, const ushort_t* __restrict__ Qbf,
                        const ushort_t* __restrict__ Mhi, const ushort_t* __restrict__ Mlo,
                        const float* __restrict__ t0g, const float* __restrict__ vg,
                        const float* __restrict__ cg, const float* __restrict__ Pg,
                        float* __restrict__ codes_out, float* __restrict__ loss_acc) {
    __shared__ __align__(16) float SH[SHF];
    float* Act = SH;
    float* Wl  = SH + WLF;
    ushort_t* h2bf = (ushort_t*)(SH + WLF);    // overlays Wl after L2
    int* flags = (int*)(SH + FLGF);
    const int t = threadIdx.x;
    const int st = t & 15, ct = t >> 4;
    const int s0 = st * 4, o0 = ct * 8;
    const int row0 = blockIdx.x * 64;

    float rb1[8], rb2[8];
#pragma unroll
    for (int i = 0; i < 8; ++i) { rb1[i] = b1[o0 + i]; rb2[i] = b2[o0 + i]; }

    // stage X^T (rows 90..95 zero-padded) — R9 verbatim
    for (int it = 0; it < 24; ++it) {
        int idx = it * 256 + t;
        int j = idx >> 6, s = idx & 63;
        Act[j * ACT_ST + s] = (j < 90) ? X[(size_t)(row0 + s) * TA + j] : 0.f;
    }

    float acc[8][4];
#pragma unroll
    for (int a = 0; a < 8; ++a)
#pragma unroll
        for (int b = 0; b < 4; ++b) acc[a][b] = 0.f;
    gemm_dbuf(w1, HID, 90, 6, Act, Wl, acc, t, o0, s0);
#pragma unroll
    for (int a = 0; a < 8; ++a)
#pragma unroll
        for (int b = 0; b < 4; ++b)
            Act[(o0 + a) * ACT_ST + s0 + b] = fmaxf(acc[a][b] + rb1[a], 0.f);

#pragma unroll
    for (int a = 0; a < 8; ++a)
#pragma unroll
        for (int b = 0; b < 4; ++b) acc[a][b] = 0.f;
    gemm_dbuf(w2, HID, 128, 8, Act, Wl, acc, t, o0, s0);

    // L2 epilogue: h2 -> Act (fp32) + h2bf (bf16 swz) — R9 verbatim
    {
#pragma unroll
        for (int b = 0; b < 4; ++b) {
            int s = s0 + b;
            bf16x8 pk;
#pragma unroll
            for (int a = 0; a < 8; ++a) {
                float hv = fmaxf(acc[a][b] + rb2[a], 0.f);
                Act[(o0 + a) * ACT_ST + s] = hv;
                pk[a] = (short)f2bf(hv);
            }
            *(bf16x8*)&h2bf[((s << 7) + o0) ^ ((s & 7) << 3)] = pk;
        }
    }
    __syncthreads();

    // ---- merged MFMA phase: U = Q*h2 (loss) and S = (Mhi+Mlo)*h2hi (scoring)
    const int wv = t >> 6, lane = t & 63, lr = lane & 15, lg = lane >> 4;
    f32x4 sc[2][4];
    {
        f32x4 qc[2][4];
#pragma unroll
        for (int m = 0; m < 2; ++m)
#pragma unroll
            for (int n = 0; n < 4; ++n) {
                qc[m][n] = (f32x4){0.f, 0.f, 0.f, 0.f};
                sc[m][n] = (f32x4){0.f, 0.f, 0.f, 0.f};
            }
#pragma unroll
        for (int kt = 0; kt < 4; ++kt) {
            bf16x8 aq[2], amh[2], aml[2], bfr[4];
#pragma unroll
            for (int m = 0; m < 2; ++m) {
                int arow = (32 * wv + 16 * m + lr) * 128 + kt * 32 + lg * 8;
                aq[m]  = *(const bf16x8*)&Qbf[arow];
                amh[m] = *(const bf16x8*)&Mhi[arow];
                aml[m] = *(const bf16x8*)&Mlo[arow];
            }
#pragma unroll
            for (int n = 0; n < 4; ++n) {
                int s = 16 * n + lr;
                bfr[n] = *(const bf16x8*)&h2bf[((s << 7) + kt * 32 + lg * 8) ^ ((s & 7) << 3)];
            }
#pragma unroll
            for (int m = 0; m < 2; ++m)
#pragma unroll
                for (int n = 0; n < 4; ++n) {
                    qc[m][n] = MFMA16(aq[m], bfr[n], qc[m][n]);
                    sc[m][n] = MFMA16(amh[m], bfr[n], sc[m][n]);
                    sc[m][n] = MFMA16(aml[m], bfr[n], sc[m][n]);
                }
        }
        // znorm partials -> PZ[4][64] (R9 verbatim; Act fp32 h2 still live)
        float v2[2][4];
#pragma unroll
        for (int m = 0; m < 2; ++m)
#pragma unroll
            for (int r = 0; r < 4; ++r) v2[m][r] = 2.f * vg[32 * wv + 16 * m + lg * 4 + r];
#pragma unroll
        for (int n = 0; n < 4; ++n) {
            int s = 16 * n + lr;
            float p = 0.f;
#pragma unroll
            for (int m = 0; m < 2; ++m)
#pragma unroll
                for (int r = 0; r < 4; ++r) {
                    int o = 32 * wv + 16 * m + lg * 4 + r;
                    p = fmaf(qc[m][n][r] + v2[m][r], Act[o * ACT_ST + s], p);
                }
            p += __shfl_xor(p, 16);
            p += __shfl_xor(p, 32);
            if (lg == 0) SH[PZF + wv * 64 + s] = p;
        }
    }
    __syncthreads();   // Act h2 reads done -> region reusable for zdot

    // dump S (+t0) as zdot, stride 129
#pragma unroll
    for (int m = 0; m < 2; ++m)
#pragma unroll
        for (int n = 0; n < 4; ++n) {
            int s = 16 * n + lr;
#pragma unroll
            for (int r = 0; r < 4; ++r) {
                int o = 32 * wv + 16 * m + lg * 4 + r;
                SH[s * 129 + o] = sc[m][n][r] + t0g[o];
            }
        }
    __syncthreads();

    // ---- phase B: fast argmin chain with margin tracking
    int cs[4];
    if (t < 64) {
        float marg = 3.4e38f;
#pragma unroll
        for (int g = 0; g < 4; ++g) {
            float best = 3.4e38f, best2 = 3.4e38f; int bi = g * 32;
#pragma unroll
            for (int k = 0; k < 32; ++k) {
                int c = g * 32 + k;
                float zd = SH[t * 129 + c];
                float nr = Pg[c * 128 + c];
                float a2 = 0.f;
#pragma unroll
                for (int gp = 0; gp < g; ++gp) a2 += Pg[cs[gp] * 128 + c];
                float dist = nr - 2.f * (zd - a2);
                if (dist < best) { best2 = best; best = dist; bi = c; }
                else if (dist < best2) { best2 = dist; }
            }
            cs[g] = bi;
            float m2 = best2 - best;
            marg = (m2 < marg) ? m2 : marg;
        }
        flags[t] = (marg < 1.5f) ? 1 : 0;
    }
    __syncthreads();

    // ---- phase C: exact recompute (bit-identical to R9 chain) for flagged
    for (int s2 = 0; s2 < 64; ++s2) {
        if (!flags[s2]) continue;               // uniform: flags in LDS
        if (t < 128) {
            float a = 0.f;
            const float* xr = X + (size_t)(row0 + s2) * TA;
            for (int j = 0; j < 90; ++j) a = fmaf(xr[j], w1[j * 128 + t], a);
            SH[H1TF + t] = fmaxf(a + b1[t], 0.f);
        }
        __syncthreads();
        if (t < 128) {
            float a = 0.f;
            for (int j = 0; j < 128; ++j) a = fmaf(SH[H1TF + j], w2[j * 128 + t], a);
            SH[H2TF + t] = fmaxf(a + b2[t], 0.f);
        }
        __syncthreads();
        if (t < 128) {
            float a = 0.f;
            for (int j = 0; j < 128; ++j) a = fmaf(SH[H2TF + j], Mt[j * 128 + t], a);
            SH[s2 * 129 + t] = a + t0g[t];
        }
        __syncthreads();
    }

    // ---- phase D: redo argmin for flagged lanes on exact zdot
    if (t < 64 && flags[t]) {
#pragma unroll
        for (int g = 0; g < 4; ++g) {
            float best = 3.4e38f; int bi = g * 32;
#pragma unroll
            for (int k = 0; k < 32; ++k) {
                int c = g * 32 + k;
                float zd = SH[t * 129 + c];
                float nr = Pg[c * 128 + c];
                float a2 = 0.f;
#pragma unroll
                for (int gp = 0; gp < g; ++gp) a2 += Pg[cs[gp] * 128 + c];
                float dist = nr - 2.f * (zd - a2);
                if (dist < best) { best = dist; bi = c; }
            }
            cs[g] = bi;
        }
    }

    // ---- loss + codes from final choices
    if (t < 64) {
        float znorm = cg[0] + SH[PZF + t] + SH[PZF + 64 + t]
                    + SH[PZF + 128 + t] + SH[PZF + 192 + t];
        float S1 = 0.f, Sp = 0.f, msum = 0.f;
#pragma unroll
        for (int g = 0; g < 4; ++g) {
            int c = cs[g];
            float zd = SH[t * 129 + c];
            float nr = Pg[c * 128 + c];
            float a2 = 0.f;
#pragma unroll
            for (int gp = 0; gp < g; ++gp) a2 += Pg[cs[gp] * 128 + c];
            S1 += zd;
            Sp += nr + 2.f * a2;
            msum += (znorm - 2.f * S1 + Sp);
            codes_out[(size_t)(row0 + t) * 4 + g] = (float)(c - g * 32);
        }
#pragma unroll
        for (int off = 32; off; off >>= 1) msum += __shfl_down(msum, off);
        if (t == 0) atomicAdd(&loss_acc[0], msum);
    }
}

// ---------------------------------------------------------------------------
// K2: quant write (fp32) + cbW-gather L1 (fp32) + bf16-MFMA decoder L2/L3.
// (R9 verbatim)
// ---------------------------------------------------------------------------
__launch_bounds__(256, 4)
__global__ void k_dec(const float* __restrict__ codes_f, const float* __restrict__ cb,
                      const float* __restrict__ cbW, const float* __restrict__ b1,
                      const ushort_t* __restrict__ w2bf, const float* __restrict__ b2,
                      const ushort_t* __restrict__ w3bf, const float* __restrict__ b3,
                      float* __restrict__ quant_out, float* __restrict__ recon_out) {
    __shared__ __align__(16) unsigned char SHB[39424];
    int* cods = (int*)SHB;
    ushort_t* h2bf = (ushort_t*)SHB;
    ushort_t* h1bf = (ushort_t*)(SHB + 16384);
    float* Rl = (float*)(SHB + 16384);
    const int t = threadIdx.x;
    const int st = t & 15, ct = t >> 4;
    const int s0 = st * 4, o0 = ct * 8;
    const int row0 = blockIdx.x * 64;

    cods[t] = ((t & 3) << 5) + (int)codes_f[(size_t)row0 * 4 + t];
    float rb1[8];
#pragma unroll
    for (int i = 0; i < 8; ++i) rb1[i] = b1[o0 + i];
    __syncthreads();

    for (int i = 0; i < 32; ++i) {
        int idx4 = i * 256 + t;
        int s = idx4 >> 7, d4 = (idx4 & 127) * 4;
        const int* cp = &cods[s * 4];
        float4 a = *(const float4*)&cb[(size_t)cp[0] * 512 + d4];
        float4 b = *(const float4*)&cb[(size_t)cp[1] * 512 + d4];
        float4 c = *(const float4*)&cb[(size_t)cp[2] * 512 + d4];
        float4 d = *(const float4*)&cb[(size_t)cp[3] * 512 + d4];
        float4 vv;
        vv.x = a.x + b.x + c.x + d.x;
        vv.y = a.y + b.y + c.y + d.y;
        vv.z = a.z + b.z + c.z + d.z;
        vv.w = a.w + b.w + c.w + d.w;
        *(float4*)&quant_out[(size_t)(row0 + s) * 512 + d4] = vv;
    }

    {
        float accL[8][4];
#pragma unroll
        for (int b = 0; b < 4; ++b) {
            const int* cp = &cods[(s0 + b) * 4];
            float u[8] = {0, 0, 0, 0, 0, 0, 0, 0};
#pragma unroll
            for (int g = 0; g < 4; ++g) {
                const float* r = &cbW[(size_t)cp[g] * 128 + o0];
                float4 x0 = *(const float4*)r, x1 = *(const float4*)(r + 4);
                u[0] += x0.x; u[1] += x0.y; u[2] += x0.z; u[3] += x0.w;
                u[4] += x1.x; u[5] += x1.y; u[6] += x1.z; u[7] += x1.w;
            }
#pragma unroll
            for (int a = 0; a < 8; ++a) accL[a][b] = u[a];
        }
#pragma unroll
        for (int b = 0; b < 4; ++b) {
            int s = s0 + b;
            bf16x8 pk;
#pragma unroll
            for (int a = 0; a < 8; ++a)
                pk[a] = (short)f2bf(fmaxf(accL[a][b] + rb1[a], 0.f));
            *(bf16x8*)&h1bf[((s << 7) + o0) ^ ((s & 7) << 3)] = pk;
        }
    }
    __syncthreads();

    const int wv = t >> 6, lane = t & 63, lr = lane & 15, lg = lane >> 4;

    {
        f32x4 c2[2][4];
#pragma unroll
        for (int m = 0; m < 2; ++m)
#pragma unroll
            for (int n = 0; n < 4; ++n) c2[m][n] = (f32x4){0.f, 0.f, 0.f, 0.f};
#pragma unroll
        for (int kt = 0; kt < 4; ++kt) {
            bf16x8 af[2], bfr[4];
#pragma unroll
            for (int m = 0; m < 2; ++m)
                af[m] = *(const bf16x8*)&w2bf[(32 * wv + 16 * m + lr) * 128 + kt * 32 + lg * 8];
#pragma unroll
            for (int n = 0; n < 4; ++n) {
                int s = 16 * n + lr;
                bfr[n] = *(const bf16x8*)&h1bf[((s << 7) + kt * 32 + lg * 8) ^ ((s & 7) << 3)];
            }
#pragma unroll
            for (int m = 0; m < 2; ++m)
#pragma unroll
                for (int n = 0; n < 4; ++n)
                    c2[m][n] = MFMA16(af[m], bfr[n], c2[m][n]);
        }
        float rb[2][4];
#pragma unroll
        for (int m = 0; m < 2; ++m)
#pragma unroll
            for (int r = 0; r < 4; ++r) rb[m][r] = b2[32 * wv + 16 * m + lg * 4 + r];
#pragma unroll
        for (int m = 0; m < 2; ++m)
#pragma unroll
            for (int n = 0; n < 4; ++n) {
                int s = 16 * n + lr;
                s16x4 pk;
#pragma unroll
                for (int r = 0; r < 4; ++r)
                    pk[r] = (short)f2bf(fmaxf(c2[m][n][r] + rb[m][r], 0.f));
                int ob2 = 32 * wv + 16 * m + lg * 4;
                *(s16x4*)&h2bf[((s << 7) + ob2) ^ ((s & 7) << 3)] = pk;
            }
    }
    __syncthreads();

    {
        f32x4 c3[6];
#pragma unroll
        for (int m = 0; m < 6; ++m) c3[m] = (f32x4){0.f, 0.f, 0.f, 0.f};
        const int sB = 16 * wv + lr;
#pragma unroll
        for (int kt = 0; kt < 4; ++kt) {
            bf16x8 bfr = *(const bf16x8*)&h2bf[((sB << 7) + kt * 32 + lg * 8) ^ ((sB & 7) << 3)];
#pragma unroll
            for (int mt = 0; mt < 6; ++mt) {
                bf16x8 af = *(const bf16x8*)&w3bf[(16 * mt + lr) * 128 + kt * 32 + lg * 8];
                c3[mt] = MFMA16(af, bfr, c3[mt]);
            }
        }
#pragma unroll
        for (int mt = 0; mt < 6; ++mt)
#pragma unroll
            for (int r = 0; r < 4; ++r) {
                int o = 16 * mt + lg * 4 + r;
                if (o < 90) Rl[sB * 90 + o] = c3[mt][r] + b3[o];
            }
    }
    __syncthreads();

    {
        const float4* R4v = (const float4*)Rl;
        float4* G4 = (float4*)(recon_out + (size_t)row0 * 90);
#pragma unroll
        for (int it = 0; it < 6; ++it) {
            int i4 = it * 256 + t;
            if (i4 < 1440) G4[i4] = R4v[i4];
        }
    }
}

// ---------------------------------------------------------------------------
__global__ void k_loss(const float* __restrict__ acc, float* __restrict__ out) {
    out[0] = acc[0] * (1.0f / ((float)NSAMP * (float)DLAT));
}

extern "C" void kernel_launch(void* const* d_in, const int* in_sizes, int n_in,
                              void* d_out, int out_size, void* d_ws, size_t ws_size,
                              hipStream_t stream) {
    const float* state  = (const float*)d_in[0];
    const float* enc_w1 = (const float*)d_in[1];
    const float* enc_b1 = (const float*)d_in[2];
    const float* enc_w2 = (const float*)d_in[3];
    const float* enc_b2 = (const float*)d_in[4];
    const float* enc_w3 = (const float*)d_in[5];
    const float* enc_b3 = (const float*)d_in[6];
    const float* dec_w1 = (const float*)d_in[7];
    const float* dec_b1 = (const float*)d_in[8];
    const float* dec_w2 = (const float*)d_in[9];
    const float* dec_b2 = (const float*)d_in[10];
    const float* dec_w3 = (const float*)d_in[11];
    const float* dec_b3 = (const float*)d_in[12];
    const float* cb     = (const float*)d_in[13];

    float* out = (float*)d_out;
    float* P   = out;
    float* M   = out + 16384;
    ushort_t* Mhi = (ushort_t*)(out + 32768);   // 16384 ushorts = 8192 floats
    ushort_t* Mlo = (ushort_t*)(out + 40960);
    float* t0  = out + 49152;
    float* v   = out + 49280;
    float* csc = out + 49408;
    float* ws = (float*)d_ws;
    float* loss_acc = ws;
    float* cbW = ws + 256;
    ushort_t* Qbf  = (ushort_t*)(ws + 16640);
    ushort_t* w2bf = (ushort_t*)(ws + 24832);
    ushort_t* w3bf = (ushort_t*)(ws + 33024);

    hipMemsetAsync(d_ws, 0, 16, stream);
    k_prep<<<448, 256, 0, stream>>>(cb, enc_w3, enc_b3, dec_w1, dec_w2, dec_w3,
                                    P, M, t0, v, csc, cbW, Qbf, w2bf, w3bf,
                                    Mhi, Mlo);
    k_encvq<<<NSAMP / 64, 256, 0, stream>>>(state, enc_w1, enc_b1, enc_w2, enc_b2,
                                            M, Qbf, Mhi, Mlo, t0, v, csc, P,
                                            out + OFF_CODE, loss_acc);
    k_dec<<<NSAMP / 64, 256, 0, stream>>>(out + OFF_CODE, cb, cbW,
                                          dec_b1, w2bf, dec_b2, w3bf, dec_b3,
                                          out, out + OFF_RECON);
    k_loss<<<1, 1, 0, stream>>>(loss_acc, out + OFF_LOSS);
}

// Round 11
// 397.830 us; speedup vs baseline: 1.5409x; 1.5409x over previous
//
#include <hip/hip_runtime.h>
#include <hip/hip_bf16.h>

#define NSAMP 131072
#define TA    90
#define HID   128
#define DLAT  512

// d_out layout (float elements): quant[N*512], code[N*4], recon[N*90], loss[1]
#define OFF_CODE  67108864ll
#define OFF_RECON (67108864ll + 524288ll)
#define OFF_LOSS  (67108864ll + 524288ll + 11796480ll)

// k_encvq LDS (floats): Act[128][68]=8704 | Wl 2x[16][128]=4096 | PZ[4][64]=256
// Act region overlays: during L1/L2 = activations; after L2 = h2hi (ushort,
// floats 0..4095) + h2lo (floats 4096..8191); after MFMA phase = zdot[64][129]
// (0..8255) | flags[64] (8256..8319) | h1tmp (8320..8447) | h2tmp (8448..8575)
#define ACT_ST 68
#define WLF    8704
#define PZF    12800
#define SHF    13056
#define FLGF   8256
#define H1TF   8320
#define H2TF   8448
#define TAU    0.0625f

typedef __attribute__((ext_vector_type(8))) short bf16x8;
typedef __attribute__((ext_vector_type(4))) short s16x4;
typedef __attribute__((ext_vector_type(4))) float f32x4;
typedef unsigned short ushort_t;
#define MFMA16(a, b, c) __builtin_amdgcn_mfma_f32_16x16x32_bf16(a, b, c, 0, 0, 0)

__device__ __forceinline__ ushort_t f2bf(float f) {
    unsigned u = __float_as_uint(f);
    u = (u + 0x7FFF + ((u >> 16) & 1)) >> 16;     // RNE
    return (ushort_t)u;
}
__device__ __forceinline__ float bf2f(ushort_t u) {
    return __uint_as_float(((unsigned)u) << 16);
}

__device__ __forceinline__ float dot512(const float* __restrict__ a,
                                        const float* __restrict__ b) {
    float s = 0.f;
    for (int i = 0; i < 128; ++i) {
        float4 x = ((const float4*)a)[i], y = ((const float4*)b)[i];
        s += x.x * y.x + x.y * y.y + x.z * y.z + x.w * y.w;
    }
    return s;
}

// ---- R9-verbatim 8x4 tile FMA ----
__device__ __forceinline__ void fma_tile(float (&acc)[8][4],
                                         const float* __restrict__ wl,
                                         const float* __restrict__ al) {
    float4 av = *(const float4*)al;
    float4 w0 = *(const float4*)wl;
    float4 w1 = *(const float4*)(wl + 4);
    float aa[4] = {av.x, av.y, av.z, av.w};
    float ww[8] = {w0.x, w0.y, w0.z, w0.w, w1.x, w1.y, w1.z, w1.w};
#pragma unroll
    for (int a = 0; a < 8; ++a)
#pragma unroll
        for (int b = 0; b < 4; ++b) acc[a][b] = fmaf(ww[a], aa[b], acc[a][b]);
}

// ---- R9-verbatim double-buffered GEMM engine ----
__device__ __forceinline__ void gemm_dbuf(const float* __restrict__ w, int wstride,
                                          int inRows, int nch,
                                          const float* __restrict__ Act,
                                          float* __restrict__ Wl,
                                          float (&acc)[8][4],
                                          int t, int o0, int s0) {
    const int wr = t >> 4;
    const int wc = (t & 15) * 8;
    float4 c0, c1;
    {
        int r = wr < inRows ? wr : inRows - 1;
        const float* p = w + (size_t)r * wstride + wc;
        c0 = *(const float4*)p; c1 = *(const float4*)(p + 4);
    }
    *(float4*)&Wl[wr * 128 + wc] = c0;
    *(float4*)&Wl[wr * 128 + wc + 4] = c1;
    __syncthreads();
    for (int ch = 0; ch < nch; ++ch) {
        const float* Wc = &Wl[(ch & 1) * 2048];
        const bool more = (ch + 1 < nch);
        if (more) {
            int rr = (ch + 1) * 16 + wr;
            int r = rr < inRows ? rr : inRows - 1;
            const float* p = w + (size_t)r * wstride + wc;
            c0 = *(const float4*)p; c1 = *(const float4*)(p + 4);
        }
        const float* Ab = Act + (ch * 16) * ACT_ST + s0;
#pragma unroll
        for (int j = 0; j < 16; ++j)
            fma_tile(acc, &Wc[j * 128 + o0], Ab + j * ACT_ST);
        __syncthreads();
        if (more) {
            float* Wn = &Wl[((ch + 1) & 1) * 2048];
            *(float4*)&Wn[wr * 128 + wc] = c0;
            *(float4*)&Wn[wr * 128 + wc + 4] = c1;
            __syncthreads();
        }
    }
}

// ---------------------------------------------------------------------------
// K0: precompute tables. tbl6: Mhi/Mlo bf16 split of M^T ([c][j]).
// ---------------------------------------------------------------------------
__global__ void k_prep(const float* __restrict__ cb, const float* __restrict__ w3,
                       const float* __restrict__ b3, const float* __restrict__ w1d,
                       const float* __restrict__ w2d, const float* __restrict__ w3d,
                       float* __restrict__ P, float* __restrict__ M,
                       float* __restrict__ t0, float* __restrict__ v,
                       float* __restrict__ csc, float* __restrict__ cbW,
                       ushort_t* __restrict__ Qbf, ushort_t* __restrict__ w2bf,
                       ushort_t* __restrict__ w3bf,
                       ushort_t* __restrict__ Mhibf, ushort_t* __restrict__ Mlobf) {
    int tbl = blockIdx.x >> 6;
    int gid = (blockIdx.x & 63) * 256 + threadIdx.x;   // 0..16383
    int i = gid >> 7, j = gid & 127;
    if (tbl == 0) {
        P[gid] = dot512(cb + (size_t)i * 512, cb + (size_t)j * 512);
        if (gid < 128) t0[gid] = dot512(cb + (size_t)gid * 512, b3);
        if (gid == 0) csc[0] = dot512(b3, b3);
    } else if (tbl == 1) {
        M[gid] = dot512(w3 + (size_t)i * 512, cb + (size_t)j * 512);
    } else if (tbl == 2) {
        Qbf[gid] = f2bf(dot512(w3 + (size_t)i * 512, w3 + (size_t)j * 512));
        if (gid < 128) v[gid] = dot512(w3 + (size_t)gid * 512, b3);
    } else if (tbl == 3) {
        float s = 0.f;
        for (int d = 0; d < 512; ++d) s = fmaf(cb[(size_t)i * 512 + d], w1d[d * 128 + j], s);
        cbW[gid] = s;
    } else if (tbl == 4) {
        w2bf[gid] = f2bf(w2d[j * 128 + i]);            // [o][j] = w2[j][o]
    } else if (tbl == 5) {
        if (gid < 96 * 128)
            w3bf[gid] = (i < 90) ? f2bf(w3d[j * TA + i]) : (ushort_t)0;
    } else {
        // tbl6: i = code c, j = hidden. M^T split hi + lo.
        float d = dot512(w3 + (size_t)j * 512, cb + (size_t)i * 512);
        ushort_t hi = f2bf(d);
        Mhibf[gid] = hi;
        Mlobf[gid] = f2bf(d - bf2f(hi));
    }
}

// ---------------------------------------------------------------------------
// K1: encoder (L1,L2 fp32) + split-bf16 MFMA scoring (3-term, err ~1e-3)
//     + Q-MFMA loss + argmin with tight-margin exact fallback (tau=1/16).
// ---------------------------------------------------------------------------
__launch_bounds__(256, 3)
__global__ void k_encvq(const float* __restrict__ X,
                        const float* __restrict__ w1, const float* __restrict__ b1,
                        const float* __restrict__ w2, const float* __restrict__ b2,
                        const float* __restrict__ Mt, const ushort_t* __restrict__ Qbf,
                        const ushort_t* __restrict__ Mhi, const ushort_t* __restrict__ Mlo,
                        const float* __restrict__ t0g, const float* __restrict__ vg,
                        const float* __restrict__ cg, const float* __restrict__ Pg,
                        float* __restrict__ codes_out, float* __restrict__ loss_acc) {
    __shared__ __align__(16) float SH[SHF];
    float* Act = SH;
    float* Wl  = SH + WLF;
    ushort_t* h2hi = (ushort_t*)SH;            // after L2: floats 0..4095
    ushort_t* h2lo = (ushort_t*)(SH + 4096);   // floats 4096..8191
    int* flags = (int*)(SH + FLGF);
    const int t = threadIdx.x;
    const int st = t & 15, ct = t >> 4;
    const int s0 = st * 4, o0 = ct * 8;
    const int row0 = blockIdx.x * 64;

    float rb1[8], rb2[8];
#pragma unroll
    for (int i = 0; i < 8; ++i) { rb1[i] = b1[o0 + i]; rb2[i] = b2[o0 + i]; }

    // stage X^T (rows 90..95 zero-padded) — R9 verbatim
    for (int it = 0; it < 24; ++it) {
        int idx = it * 256 + t;
        int j = idx >> 6, s = idx & 63;
        Act[j * ACT_ST + s] = (j < 90) ? X[(size_t)(row0 + s) * TA + j] : 0.f;
    }

    float acc[8][4];
#pragma unroll
    for (int a = 0; a < 8; ++a)
#pragma unroll
        for (int b = 0; b < 4; ++b) acc[a][b] = 0.f;
    gemm_dbuf(w1, HID, 90, 6, Act, Wl, acc, t, o0, s0);
#pragma unroll
    for (int a = 0; a < 8; ++a)
#pragma unroll
        for (int b = 0; b < 4; ++b)
            Act[(o0 + a) * ACT_ST + s0 + b] = fmaxf(acc[a][b] + rb1[a], 0.f);

#pragma unroll
    for (int a = 0; a < 8; ++a)
#pragma unroll
        for (int b = 0; b < 4; ++b) acc[a][b] = 0.f;
    gemm_dbuf(w2, HID, 128, 8, Act, Wl, acc, t, o0, s0);
    // (gemm's trailing barrier: all h1 reads done -> Act region reusable)

    // L2 epilogue: h2 split into h2hi + h2lo (bf16, swizzled) in Act region
    {
#pragma unroll
        for (int b = 0; b < 4; ++b) {
            int s = s0 + b;
            bf16x8 pkh, pkl;
#pragma unroll
            for (int a = 0; a < 8; ++a) {
                float hv = fmaxf(acc[a][b] + rb2[a], 0.f);
                ushort_t hi = f2bf(hv);
                pkh[a] = (short)hi;
                pkl[a] = (short)f2bf(hv - bf2f(hi));
            }
            int adr = ((s << 7) + o0) ^ ((s & 7) << 3);
            *(bf16x8*)&h2hi[adr] = pkh;
            *(bf16x8*)&h2lo[adr] = pkl;
        }
    }
    __syncthreads();

    // ---- MFMA phase: qc = Q*h2hi (loss); sc = Mhi*hi + Mhi*lo + Mlo*hi
    const int wv = t >> 6, lane = t & 63, lr = lane & 15, lg = lane >> 4;
    f32x4 sc[2][4];
    {
        f32x4 qc[2][4];
#pragma unroll
        for (int m = 0; m < 2; ++m)
#pragma unroll
            for (int n = 0; n < 4; ++n) {
                qc[m][n] = (f32x4){0.f, 0.f, 0.f, 0.f};
                sc[m][n] = (f32x4){0.f, 0.f, 0.f, 0.f};
            }
#pragma unroll
        for (int kt = 0; kt < 4; ++kt) {
            bf16x8 aq[2], amh[2], aml[2], bhi[4], blo[4];
#pragma unroll
            for (int m = 0; m < 2; ++m) {
                int arow = (32 * wv + 16 * m + lr) * 128 + kt * 32 + lg * 8;
                aq[m]  = *(const bf16x8*)&Qbf[arow];
                amh[m] = *(const bf16x8*)&Mhi[arow];
                aml[m] = *(const bf16x8*)&Mlo[arow];
            }
#pragma unroll
            for (int n = 0; n < 4; ++n) {
                int s = 16 * n + lr;
                int adr = ((s << 7) + kt * 32 + lg * 8) ^ ((s & 7) << 3);
                bhi[n] = *(const bf16x8*)&h2hi[adr];
                blo[n] = *(const bf16x8*)&h2lo[adr];
            }
#pragma unroll
            for (int m = 0; m < 2; ++m)
#pragma unroll
                for (int n = 0; n < 4; ++n) {
                    qc[m][n] = MFMA16(aq[m], bhi[n], qc[m][n]);
                    sc[m][n] = MFMA16(amh[m], bhi[n], sc[m][n]);
                    sc[m][n] = MFMA16(amh[m], blo[n], sc[m][n]);
                    sc[m][n] = MFMA16(aml[m], bhi[n], sc[m][n]);
                }
        }
        // znorm partials -> PZ[4][64]; h2 = hi + lo (2^-17-exact)
        float v2[2][4];
#pragma unroll
        for (int m = 0; m < 2; ++m)
#pragma unroll
            for (int r = 0; r < 4; ++r) v2[m][r] = 2.f * vg[32 * wv + 16 * m + lg * 4 + r];
#pragma unroll
        for (int n = 0; n < 4; ++n) {
            int s = 16 * n + lr;
            float p = 0.f;
#pragma unroll
            for (int m = 0; m < 2; ++m)
#pragma unroll
                for (int r = 0; r < 4; ++r) {
                    int o = 32 * wv + 16 * m + lg * 4 + r;
                    int adr = ((s << 7) + o) ^ ((s & 7) << 3);
                    float hv = bf2f(h2hi[adr]) + bf2f(h2lo[adr]);
                    p = fmaf(qc[m][n][r] + v2[m][r], hv, p);
                }
            p += __shfl_xor(p, 16);
            p += __shfl_xor(p, 32);
            if (lg == 0) SH[PZF + wv * 64 + s] = p;
        }
    }
    __syncthreads();   // all h2hi/h2lo reads done -> region reusable for zdot

    // dump S (+t0) as zdot, stride 129
#pragma unroll
    for (int m = 0; m < 2; ++m)
#pragma unroll
        for (int n = 0; n < 4; ++n) {
            int s = 16 * n + lr;
#pragma unroll
            for (int r = 0; r < 4; ++r) {
                int o = 32 * wv + 16 * m + lg * 4 + r;
                SH[s * 129 + o] = sc[m][n][r] + t0g[o];
            }
        }
    __syncthreads();

    // ---- fast argmin chain with margin tracking
    int cs[4];
    if (t < 64) {
        float marg = 3.4e38f;
#pragma unroll
        for (int g = 0; g < 4; ++g) {
            float best = 3.4e38f, best2 = 3.4e38f; int bi = g * 32;
#pragma unroll
            for (int k = 0; k < 32; ++k) {
                int c = g * 32 + k;
                float zd = SH[t * 129 + c];
                float nr = Pg[c * 128 + c];
                float a2 = 0.f;
#pragma unroll
                for (int gp = 0; gp < g; ++gp) a2 += Pg[cs[gp] * 128 + c];
                float dist = nr - 2.f * (zd - a2);
                if (dist < best) { best2 = best; best = dist; bi = c; }
                else if (dist < best2) { best2 = dist; }
            }
            cs[g] = bi;
            float m2 = best2 - best;
            marg = (m2 < marg) ? m2 : marg;
        }
        flags[t] = (marg < TAU) ? 1 : 0;
    }
    __syncthreads();

    // ---- exact recompute (bit-identical to R9 chain) for flagged samples
    for (int s2 = 0; s2 < 64; ++s2) {
        if (!flags[s2]) continue;               // uniform branch (LDS value)
        if (t < 128) {
            float a = 0.f;
            const float* xr = X + (size_t)(row0 + s2) * TA;
            for (int j = 0; j < 90; ++j) a = fmaf(xr[j], w1[j * 128 + t], a);
            SH[H1TF + t] = fmaxf(a + b1[t], 0.f);
        }
        __syncthreads();
        if (t < 128) {
            float a = 0.f;
            for (int j = 0; j < 128; ++j) a = fmaf(SH[H1TF + j], w2[j * 128 + t], a);
            SH[H2TF + t] = fmaxf(a + b2[t], 0.f);
        }
        __syncthreads();
        if (t < 128) {
            float a = 0.f;
            for (int j = 0; j < 128; ++j) a = fmaf(SH[H2TF + j], Mt[j * 128 + t], a);
            SH[s2 * 129 + t] = a + t0g[t];
        }
        __syncthreads();
    }

    // ---- redo argmin for flagged lanes on exact zdot
    if (t < 64 && flags[t]) {
#pragma unroll
        for (int g = 0; g < 4; ++g) {
            float best = 3.4e38f; int bi = g * 32;
#pragma unroll
            for (int k = 0; k < 32; ++k) {
                int c = g * 32 + k;
                float zd = SH[t * 129 + c];
                float nr = Pg[c * 128 + c];
                float a2 = 0.f;
#pragma unroll
                for (int gp = 0; gp < g; ++gp) a2 += Pg[cs[gp] * 128 + c];
                float dist = nr - 2.f * (zd - a2);
                if (dist < best) { best = dist; bi = c; }
            }
            cs[g] = bi;
        }
    }

    // ---- loss + codes from final choices
    if (t < 64) {
        float znorm = cg[0] + SH[PZF + t] + SH[PZF + 64 + t]
                    + SH[PZF + 128 + t] + SH[PZF + 192 + t];
        float S1 = 0.f, Sp = 0.f, msum = 0.f;
#pragma unroll
        for (int g = 0; g < 4; ++g) {
            int c = cs[g];
            float zd = SH[t * 129 + c];
            float nr = Pg[c * 128 + c];
            float a2 = 0.f;
#pragma unroll
            for (int gp = 0; gp < g; ++gp) a2 += Pg[cs[gp] * 128 + c];
            S1 += zd;
            Sp += nr + 2.f * a2;
            msum += (znorm - 2.f * S1 + Sp);
            codes_out[(size_t)(row0 + t) * 4 + g] = (float)(c - g * 32);
        }
#pragma unroll
        for (int off = 32; off; off >>= 1) msum += __shfl_down(msum, off);
        if (t == 0) atomicAdd(&loss_acc[0], msum);
    }
}

// ---------------------------------------------------------------------------
// K2: quant write (fp32) + cbW-gather L1 (fp32) + bf16-MFMA decoder L2/L3.
// (R9 verbatim)
// ---------------------------------------------------------------------------
__launch_bounds__(256, 4)
__global__ void k_dec(const float* __restrict__ codes_f, const float* __restrict__ cb,
                      const float* __restrict__ cbW, const float* __restrict__ b1,
                      const ushort_t* __restrict__ w2bf, const float* __restrict__ b2,
                      const ushort_t* __restrict__ w3bf, const float* __restrict__ b3,
                      float* __restrict__ quant_out, float* __restrict__ recon_out) {
    __shared__ __align__(16) unsigned char SHB[39424];
    int* cods = (int*)SHB;
    ushort_t* h2bf = (ushort_t*)SHB;
    ushort_t* h1bf = (ushort_t*)(SHB + 16384);
    float* Rl = (float*)(SHB + 16384);
    const int t = threadIdx.x;
    const int st = t & 15, ct = t >> 4;
    const int s0 = st * 4, o0 = ct * 8;
    const int row0 = blockIdx.x * 64;

    cods[t] = ((t & 3) << 5) + (int)codes_f[(size_t)row0 * 4 + t];
    float rb1[8];
#pragma unroll
    for (int i = 0; i < 8; ++i) rb1[i] = b1[o0 + i];
    __syncthreads();

    for (int i = 0; i < 32; ++i) {
        int idx4 = i * 256 + t;
        int s = idx4 >> 7, d4 = (idx4 & 127) * 4;
        const int* cp = &cods[s * 4];
        float4 a = *(const float4*)&cb[(size_t)cp[0] * 512 + d4];
        float4 b = *(const float4*)&cb[(size_t)cp[1] * 512 + d4];
        float4 c = *(const float4*)&cb[(size_t)cp[2] * 512 + d4];
        float4 d = *(const float4*)&cb[(size_t)cp[3] * 512 + d4];
        float4 vv;
        vv.x = a.x + b.x + c.x + d.x;
        vv.y = a.y + b.y + c.y + d.y;
        vv.z = a.z + b.z + c.z + d.z;
        vv.w = a.w + b.w + c.w + d.w;
        *(float4*)&quant_out[(size_t)(row0 + s) * 512 + d4] = vv;
    }

    {
        float accL[8][4];
#pragma unroll
        for (int b = 0; b < 4; ++b) {
            const int* cp = &cods[(s0 + b) * 4];
            float u[8] = {0, 0, 0, 0, 0, 0, 0, 0};
#pragma unroll
            for (int g = 0; g < 4; ++g) {
                const float* r = &cbW[(size_t)cp[g] * 128 + o0];
                float4 x0 = *(const float4*)r, x1 = *(const float4*)(r + 4);
                u[0] += x0.x; u[1] += x0.y; u[2] += x0.z; u[3] += x0.w;
                u[4] += x1.x; u[5] += x1.y; u[6] += x1.z; u[7] += x1.w;
            }
#pragma unroll
            for (int a = 0; a < 8; ++a) accL[a][b] = u[a];
        }
#pragma unroll
        for (int b = 0; b < 4; ++b) {
            int s = s0 + b;
            bf16x8 pk;
#pragma unroll
            for (int a = 0; a < 8; ++a)
                pk[a] = (short)f2bf(fmaxf(accL[a][b] + rb1[a], 0.f));
            *(bf16x8*)&h1bf[((s << 7) + o0) ^ ((s & 7) << 3)] = pk;
        }
    }
    __syncthreads();

    const int wv = t >> 6, lane = t & 63, lr = lane & 15, lg = lane >> 4;

    {
        f32x4 c2[2][4];
#pragma unroll
        for (int m = 0; m < 2; ++m)
#pragma unroll
            for (int n = 0; n < 4; ++n) c2[m][n] = (f32x4){0.f, 0.f, 0.f, 0.f};
#pragma unroll
        for (int kt = 0; kt < 4; ++kt) {
            bf16x8 af[2], bfr[4];
#pragma unroll
            for (int m = 0; m < 2; ++m)
                af[m] = *(const bf16x8*)&w2bf[(32 * wv + 16 * m + lr) * 128 + kt * 32 + lg * 8];
#pragma unroll
            for (int n = 0; n < 4; ++n) {
                int s = 16 * n + lr;
                bfr[n] = *(const bf16x8*)&h1bf[((s << 7) + kt * 32 + lg * 8) ^ ((s & 7) << 3)];
            }
#pragma unroll
            for (int m = 0; m < 2; ++m)
#pragma unroll
                for (int n = 0; n < 4; ++n)
                    c2[m][n] = MFMA16(af[m], bfr[n], c2[m][n]);
        }
        float rb[2][4];
#pragma unroll
        for (int m = 0; m < 2; ++m)
#pragma unroll
            for (int r = 0; r < 4; ++r) rb[m][r] = b2[32 * wv + 16 * m + lg * 4 + r];
#pragma unroll
        for (int m = 0; m < 2; ++m)
#pragma unroll
            for (int n = 0; n < 4; ++n) {
                int s = 16 * n + lr;
                s16x4 pk;
#pragma unroll
                for (int r = 0; r < 4; ++r)
                    pk[r] = (short)f2bf(fmaxf(c2[m][n][r] + rb[m][r], 0.f));
                int ob2 = 32 * wv + 16 * m + lg * 4;
                *(s16x4*)&h2bf[((s << 7) + ob2) ^ ((s & 7) << 3)] = pk;
            }
    }
    __syncthreads();

    {
        f32x4 c3[6];
#pragma unroll
        for (int m = 0; m < 6; ++m) c3[m] = (f32x4){0.f, 0.f, 0.f, 0.f};
        const int sB = 16 * wv + lr;
#pragma unroll
        for (int kt = 0; kt < 4; ++kt) {
            bf16x8 bfr = *(const bf16x8*)&h2bf[((sB << 7) + kt * 32 + lg * 8) ^ ((sB & 7) << 3)];
#pragma unroll
            for (int mt = 0; mt < 6; ++mt) {
                bf16x8 af = *(const bf16x8*)&w3bf[(16 * mt + lr) * 128 + kt * 32 + lg * 8];
                c3[mt] = MFMA16(af, bfr, c3[mt]);
            }
        }
#pragma unroll
        for (int mt = 0; mt < 6; ++mt)
#pragma unroll
            for (int r = 0; r < 4; ++r) {
                int o = 16 * mt + lg * 4 + r;
                if (o < 90) Rl[sB * 90 + o] = c3[mt][r] + b3[o];
            }
    }
    __syncthreads();

    {
        const float4* R4v = (const float4*)Rl;
        float4* G4 = (float4*)(recon_out + (size_t)row0 * 90);
#pragma unroll
        for (int it = 0; it < 6; ++it) {
            int i4 = it * 256 + t;
            if (i4 < 1440) G4[i4] = R4v[i4];
        }
    }
}

// ---------------------------------------------------------------------------
__global__ void k_loss(const float* __restrict__ acc, float* __restrict__ out) {
    out[0] = acc[0] * (1.0f / ((float)NSAMP * (float)DLAT));
}

extern "C" void kernel_launch(void* const* d_in, const int* in_sizes, int n_in,
                              void* d_out, int out_size, void* d_ws, size_t ws_size,
                              hipStream_t stream) {
    const float* state  = (const float*)d_in[0];
    const float* enc_w1 = (const float*)d_in[1];
    const float* enc_b1 = (const float*)d_in[2];
    const float* enc_w2 = (const float*)d_in[3];
    const float* enc_b2 = (const float*)d_in[4];
    const float* enc_w3 = (const float*)d_in[5];
    const float* enc_b3 = (const float*)d_in[6];
    const float* dec_w1 = (const float*)d_in[7];
    const float* dec_b1 = (const float*)d_in[8];
    const float* dec_w2 = (const float*)d_in[9];
    const float* dec_b2 = (const float*)d_in[10];
    const float* dec_w3 = (const float*)d_in[11];
    const float* dec_b3 = (const float*)d_in[12];
    const float* cb     = (const float*)d_in[13];

    float* out = (float*)d_out;
    float* P   = out;
    float* M   = out + 16384;
    ushort_t* Mhi = (ushort_t*)(out + 32768);
    ushort_t* Mlo = (ushort_t*)(out + 40960);
    float* t0  = out + 49152;
    float* v   = out + 49280;
    float* csc = out + 49408;
    float* ws = (float*)d_ws;
    float* loss_acc = ws;
    float* cbW = ws + 256;
    ushort_t* Qbf  = (ushort_t*)(ws + 16640);
    ushort_t* w2bf = (ushort_t*)(ws + 24832);
    ushort_t* w3bf = (ushort_t*)(ws + 33024);

    hipMemsetAsync(d_ws, 0, 16, stream);
    k_prep<<<448, 256, 0, stream>>>(cb, enc_w3, enc_b3, dec_w1, dec_w2, dec_w3,
                                    P, M, t0, v, csc, cbW, Qbf, w2bf, w3bf,
                                    Mhi, Mlo);
    k_encvq<<<NSAMP / 64, 256, 0, stream>>>(state, enc_w1, enc_b1, enc_w2, enc_b2,
                                            M, Qbf, Mhi, Mlo, t0, v, csc, P,
                                            out + OFF_CODE, loss_acc);
    k_dec<<<NSAMP / 64, 256, 0, stream>>>(out + OFF_CODE, cb, cbW,
                                          dec_b1, w2bf, dec_b2, w3bf, dec_b3,
                                          out, out + OFF_RECON);
    k_loss<<<1, 1, 0, stream>>>(loss_acc, out + OFF_LOSS);
}

// Round 12
// 376.515 us; speedup vs baseline: 1.6281x; 1.0566x over previous
//
#include <hip/hip_runtime.h>
#include <hip/hip_bf16.h>

#define NSAMP 131072
#define TA    90
#define HID   128
#define DLAT  512

// d_out layout (float elements): quant[N*512], code[N*4], recon[N*90], loss[1]
#define OFF_CODE  67108864ll
#define OFF_RECON (67108864ll + 524288ll)
#define OFF_LOSS  (67108864ll + 524288ll + 11796480ll)

// k_encvq LDS (floats): Act[128][68]=8704 | Wl 2x[16][128]=4096 | PZ[4][64]=256
// Act overlays: L1/L2 = activations; after L2 = h2hi (0..4095) + h2lo
// (4096..8191); after MFMA = zdot[64][129] (0..8255) | mask (8256..8257) |
// H2A (8272..8399) | H2B (8400..8527)
#define ACT_ST 68
#define WLF    8704
#define PZF    12800
#define SHF    13056
#define MSKF   8256
#define H2AF   8272
#define H2BF   8400
#define TAU    0.0625f

typedef __attribute__((ext_vector_type(8))) short bf16x8;
typedef __attribute__((ext_vector_type(4))) short s16x4;
typedef __attribute__((ext_vector_type(4))) float f32x4;
typedef unsigned short ushort_t;
#define MFMA16(a, b, c) __builtin_amdgcn_mfma_f32_16x16x32_bf16(a, b, c, 0, 0, 0)

__device__ __forceinline__ ushort_t f2bf(float f) {
    unsigned u = __float_as_uint(f);
    u = (u + 0x7FFF + ((u >> 16) & 1)) >> 16;     // RNE
    return (ushort_t)u;
}
__device__ __forceinline__ float bf2f(ushort_t u) {
    return __uint_as_float(((unsigned)u) << 16);
}

__device__ __forceinline__ float dot512(const float* __restrict__ a,
                                        const float* __restrict__ b) {
    float s = 0.f;
    for (int i = 0; i < 128; ++i) {
        float4 x = ((const float4*)a)[i], y = ((const float4*)b)[i];
        s += x.x * y.x + x.y * y.y + x.z * y.z + x.w * y.w;
    }
    return s;
}

// ---- R9-verbatim 8x4 tile FMA ----
__device__ __forceinline__ void fma_tile(float (&acc)[8][4],
                                         const float* __restrict__ wl,
                                         const float* __restrict__ al) {
    float4 av = *(const float4*)al;
    float4 w0 = *(const float4*)wl;
    float4 w1 = *(const float4*)(wl + 4);
    float aa[4] = {av.x, av.y, av.z, av.w};
    float ww[8] = {w0.x, w0.y, w0.z, w0.w, w1.x, w1.y, w1.z, w1.w};
#pragma unroll
    for (int a = 0; a < 8; ++a)
#pragma unroll
        for (int b = 0; b < 4; ++b) acc[a][b] = fmaf(ww[a], aa[b], acc[a][b]);
}

// ---- R9-verbatim double-buffered GEMM engine ----
__device__ __forceinline__ void gemm_dbuf(const float* __restrict__ w, int wstride,
                                          int inRows, int nch,
                                          const float* __restrict__ Act,
                                          float* __restrict__ Wl,
                                          float (&acc)[8][4],
                                          int t, int o0, int s0) {
    const int wr = t >> 4;
    const int wc = (t & 15) * 8;
    float4 c0, c1;
    {
        int r = wr < inRows ? wr : inRows - 1;
        const float* p = w + (size_t)r * wstride + wc;
        c0 = *(const float4*)p; c1 = *(const float4*)(p + 4);
    }
    *(float4*)&Wl[wr * 128 + wc] = c0;
    *(float4*)&Wl[wr * 128 + wc + 4] = c1;
    __syncthreads();
    for (int ch = 0; ch < nch; ++ch) {
        const float* Wc = &Wl[(ch & 1) * 2048];
        const bool more = (ch + 1 < nch);
        if (more) {
            int rr = (ch + 1) * 16 + wr;
            int r = rr < inRows ? rr : inRows - 1;
            const float* p = w + (size_t)r * wstride + wc;
            c0 = *(const float4*)p; c1 = *(const float4*)(p + 4);
        }
        const float* Ab = Act + (ch * 16) * ACT_ST + s0;
#pragma unroll
        for (int j = 0; j < 16; ++j)
            fma_tile(acc, &Wc[j * 128 + o0], Ab + j * ACT_ST);
        __syncthreads();
        if (more) {
            float* Wn = &Wl[((ch + 1) & 1) * 2048];
            *(float4*)&Wn[wr * 128 + wc] = c0;
            *(float4*)&Wn[wr * 128 + wc + 4] = c1;
            __syncthreads();
        }
    }
}

// ---------------------------------------------------------------------------
// K0: precompute tables. tbl6: Mhi/Mlo bf16 split of M^T ([c][j]).
// ---------------------------------------------------------------------------
__global__ void k_prep(const float* __restrict__ cb, const float* __restrict__ w3,
                       const float* __restrict__ b3, const float* __restrict__ w1d,
                       const float* __restrict__ w2d, const float* __restrict__ w3d,
                       float* __restrict__ P, float* __restrict__ M,
                       float* __restrict__ t0, float* __restrict__ v,
                       float* __restrict__ csc, float* __restrict__ cbW,
                       ushort_t* __restrict__ Qbf, ushort_t* __restrict__ w2bf,
                       ushort_t* __restrict__ w3bf,
                       ushort_t* __restrict__ Mhibf, ushort_t* __restrict__ Mlobf) {
    int tbl = blockIdx.x >> 6;
    int gid = (blockIdx.x & 63) * 256 + threadIdx.x;   // 0..16383
    int i = gid >> 7, j = gid & 127;
    if (tbl == 0) {
        P[gid] = dot512(cb + (size_t)i * 512, cb + (size_t)j * 512);
        if (gid < 128) t0[gid] = dot512(cb + (size_t)gid * 512, b3);
        if (gid == 0) csc[0] = dot512(b3, b3);
    } else if (tbl == 1) {
        M[gid] = dot512(w3 + (size_t)i * 512, cb + (size_t)j * 512);
    } else if (tbl == 2) {
        Qbf[gid] = f2bf(dot512(w3 + (size_t)i * 512, w3 + (size_t)j * 512));
        if (gid < 128) v[gid] = dot512(w3 + (size_t)gid * 512, b3);
    } else if (tbl == 3) {
        float s = 0.f;
        for (int d = 0; d < 512; ++d) s = fmaf(cb[(size_t)i * 512 + d], w1d[d * 128 + j], s);
        cbW[gid] = s;
    } else if (tbl == 4) {
        w2bf[gid] = f2bf(w2d[j * 128 + i]);            // [o][j] = w2[j][o]
    } else if (tbl == 5) {
        if (gid < 96 * 128)
            w3bf[gid] = (i < 90) ? f2bf(w3d[j * TA + i]) : (ushort_t)0;
    } else {
        // tbl6: i = code c, j = hidden. M^T split hi + lo.
        float d = dot512(w3 + (size_t)j * 512, cb + (size_t)i * 512);
        ushort_t hi = f2bf(d);
        Mhibf[gid] = hi;
        Mlobf[gid] = f2bf(d - bf2f(hi));
    }
}

// ---------------------------------------------------------------------------
// K1: encoder (L1,L2 fp32) + split-bf16 MFMA scoring + Q-MFMA loss + argmin
//     with pair-parallel exact zdot fallback from register-held h2.
// ---------------------------------------------------------------------------
__launch_bounds__(256, 3)
__global__ void k_encvq(const float* __restrict__ X,
                        const float* __restrict__ w1, const float* __restrict__ b1,
                        const float* __restrict__ w2, const float* __restrict__ b2,
                        const float* __restrict__ Mt, const ushort_t* __restrict__ Qbf,
                        const ushort_t* __restrict__ Mhi, const ushort_t* __restrict__ Mlo,
                        const float* __restrict__ t0g, const float* __restrict__ vg,
                        const float* __restrict__ cg, const float* __restrict__ Pg,
                        float* __restrict__ codes_out, float* __restrict__ loss_acc) {
    __shared__ __align__(16) float SH[SHF];
    float* Act = SH;
    float* Wl  = SH + WLF;
    ushort_t* h2hi = (ushort_t*)SH;            // after L2: floats 0..4095
    ushort_t* h2lo = (ushort_t*)(SH + 4096);   // floats 4096..8191
    const int t = threadIdx.x;
    const int st = t & 15, ct = t >> 4;
    const int s0 = st * 4, o0 = ct * 8;
    const int row0 = blockIdx.x * 64;

    float rb1[8], rb2[8];
#pragma unroll
    for (int i = 0; i < 8; ++i) { rb1[i] = b1[o0 + i]; rb2[i] = b2[o0 + i]; }

    // stage X^T (rows 90..95 zero-padded) — R9 verbatim
    for (int it = 0; it < 24; ++it) {
        int idx = it * 256 + t;
        int j = idx >> 6, s = idx & 63;
        Act[j * ACT_ST + s] = (j < 90) ? X[(size_t)(row0 + s) * TA + j] : 0.f;
    }

    float acc[8][4];
#pragma unroll
    for (int a = 0; a < 8; ++a)
#pragma unroll
        for (int b = 0; b < 4; ++b) acc[a][b] = 0.f;
    gemm_dbuf(w1, HID, 90, 6, Act, Wl, acc, t, o0, s0);
#pragma unroll
    for (int a = 0; a < 8; ++a)
#pragma unroll
        for (int b = 0; b < 4; ++b)
            Act[(o0 + a) * ACT_ST + s0 + b] = fmaxf(acc[a][b] + rb1[a], 0.f);

#pragma unroll
    for (int a = 0; a < 8; ++a)
#pragma unroll
        for (int b = 0; b < 4; ++b) acc[a][b] = 0.f;
    gemm_dbuf(w2, HID, 128, 8, Act, Wl, acc, t, o0, s0);
    // (gemm's trailing barrier: all h1 reads done -> Act region reusable)

    // L2 epilogue: h2 = relu(acc+b2) kept EXACT in acc (registers) + split
    // into h2hi/h2lo (bf16, swizzled) in the Act LDS region.
    {
#pragma unroll
        for (int b = 0; b < 4; ++b) {
            int s = s0 + b;
            bf16x8 pkh, pkl;
#pragma unroll
            for (int a = 0; a < 8; ++a) {
                float hv = fmaxf(acc[a][b] + rb2[a], 0.f);
                acc[a][b] = hv;                       // exact h2 stays in regs
                ushort_t hi = f2bf(hv);
                pkh[a] = (short)hi;
                pkl[a] = (short)f2bf(hv - bf2f(hi));
            }
            int adr = ((s << 7) + o0) ^ ((s & 7) << 3);
            *(bf16x8*)&h2hi[adr] = pkh;
            *(bf16x8*)&h2lo[adr] = pkl;
        }
    }
    __syncthreads();

    // ---- MFMA phase: qc = Q*h2hi (loss); sc = Mhi*hi + Mhi*lo + Mlo*hi
    const int wv = t >> 6, lane = t & 63, lr = lane & 15, lg = lane >> 4;
    f32x4 sc[2][4];
    {
        f32x4 qc[2][4];
#pragma unroll
        for (int m = 0; m < 2; ++m)
#pragma unroll
            for (int n = 0; n < 4; ++n) {
                qc[m][n] = (f32x4){0.f, 0.f, 0.f, 0.f};
                sc[m][n] = (f32x4){0.f, 0.f, 0.f, 0.f};
            }
#pragma unroll
        for (int kt = 0; kt < 4; ++kt) {
            bf16x8 aq[2], amh[2], aml[2], bhi[4], blo[4];
#pragma unroll
            for (int m = 0; m < 2; ++m) {
                int arow = (32 * wv + 16 * m + lr) * 128 + kt * 32 + lg * 8;
                aq[m]  = *(const bf16x8*)&Qbf[arow];
                amh[m] = *(const bf16x8*)&Mhi[arow];
                aml[m] = *(const bf16x8*)&Mlo[arow];
            }
#pragma unroll
            for (int n = 0; n < 4; ++n) {
                int s = 16 * n + lr;
                int adr = ((s << 7) + kt * 32 + lg * 8) ^ ((s & 7) << 3);
                bhi[n] = *(const bf16x8*)&h2hi[adr];
                blo[n] = *(const bf16x8*)&h2lo[adr];
            }
#pragma unroll
            for (int m = 0; m < 2; ++m)
#pragma unroll
                for (int n = 0; n < 4; ++n) {
                    qc[m][n] = MFMA16(aq[m], bhi[n], qc[m][n]);
                    sc[m][n] = MFMA16(amh[m], bhi[n], sc[m][n]);
                    sc[m][n] = MFMA16(amh[m], blo[n], sc[m][n]);
                    sc[m][n] = MFMA16(aml[m], bhi[n], sc[m][n]);
                }
        }
        // znorm partials -> PZ[4][64]; h2 = hi + lo (2^-17-exact)
        float v2[2][4];
#pragma unroll
        for (int m = 0; m < 2; ++m)
#pragma unroll
            for (int r = 0; r < 4; ++r) v2[m][r] = 2.f * vg[32 * wv + 16 * m + lg * 4 + r];
#pragma unroll
        for (int n = 0; n < 4; ++n) {
            int s = 16 * n + lr;
            float p = 0.f;
#pragma unroll
            for (int m = 0; m < 2; ++m)
#pragma unroll
                for (int r = 0; r < 4; ++r) {
                    int o = 32 * wv + 16 * m + lg * 4 + r;
                    int adr = ((s << 7) + o) ^ ((s & 7) << 3);
                    float hv = bf2f(h2hi[adr]) + bf2f(h2lo[adr]);
                    p = fmaf(qc[m][n][r] + v2[m][r], hv, p);
                }
            p += __shfl_xor(p, 16);
            p += __shfl_xor(p, 32);
            if (lg == 0) SH[PZF + wv * 64 + s] = p;
        }
    }
    __syncthreads();   // all h2hi/h2lo reads done -> region reusable for zdot

    // dump S (+t0) as zdot, stride 129
#pragma unroll
    for (int m = 0; m < 2; ++m)
#pragma unroll
        for (int n = 0; n < 4; ++n) {
            int s = 16 * n + lr;
#pragma unroll
            for (int r = 0; r < 4; ++r) {
                int o = 32 * wv + 16 * m + lg * 4 + r;
                SH[s * 129 + o] = sc[m][n][r] + t0g[o];
            }
        }
    __syncthreads();

    // ---- fast argmin chain with margin tracking; wave-0 ballot -> mask
    int cs[4];
    if (t < 64) {
        float marg = 3.4e38f;
#pragma unroll
        for (int g = 0; g < 4; ++g) {
            float best = 3.4e38f, best2 = 3.4e38f; int bi = g * 32;
#pragma unroll
            for (int k = 0; k < 32; ++k) {
                int c = g * 32 + k;
                float zd = SH[t * 129 + c];
                float nr = Pg[c * 128 + c];
                float a2 = 0.f;
#pragma unroll
                for (int gp = 0; gp < g; ++gp) a2 += Pg[cs[gp] * 128 + c];
                float dist = nr - 2.f * (zd - a2);
                if (dist < best) { best2 = best; best = dist; bi = c; }
                else if (dist < best2) { best2 = dist; }
            }
            cs[g] = bi;
            float m2 = best2 - best;
            marg = (m2 < marg) ? m2 : marg;
        }
        unsigned long long mk = __ballot(marg < TAU);
        if (t == 0) *(unsigned long long*)&SH[MSKF] = mk;
    }
    __syncthreads();

    const unsigned long long mask = *(const unsigned long long*)&SH[MSKF];

    // ---- exact zdot recompute for flagged samples, two at a time.
    // h2 source = register-held exact fp32 (identical to R9's engine output);
    // ascending-j fmaf == R9's M-GEMM chain bit-for-bit.
    {
        unsigned long long mk = mask;
        while (mk) {
            int nA = (int)__ffsll((long long)mk) - 1; mk &= mk - 1;
            int nB = -1;
            if (mk) { nB = (int)__ffsll((long long)mk) - 1; mk &= mk - 1; }
            if ((t & 15) == (nA >> 2)) {
                int bb = nA & 3;
                if (bb == 0) {
#pragma unroll
                    for (int a = 0; a < 8; ++a) SH[H2AF + o0 + a] = acc[a][0];
                } else if (bb == 1) {
#pragma unroll
                    for (int a = 0; a < 8; ++a) SH[H2AF + o0 + a] = acc[a][1];
                } else if (bb == 2) {
#pragma unroll
                    for (int a = 0; a < 8; ++a) SH[H2AF + o0 + a] = acc[a][2];
                } else {
#pragma unroll
                    for (int a = 0; a < 8; ++a) SH[H2AF + o0 + a] = acc[a][3];
                }
            }
            if (nB >= 0 && (t & 15) == (nB >> 2)) {
                int bb = nB & 3;
                if (bb == 0) {
#pragma unroll
                    for (int a = 0; a < 8; ++a) SH[H2BF + o0 + a] = acc[a][0];
                } else if (bb == 1) {
#pragma unroll
                    for (int a = 0; a < 8; ++a) SH[H2BF + o0 + a] = acc[a][1];
                } else if (bb == 2) {
#pragma unroll
                    for (int a = 0; a < 8; ++a) SH[H2BF + o0 + a] = acc[a][2];
                } else {
#pragma unroll
                    for (int a = 0; a < 8; ++a) SH[H2BF + o0 + a] = acc[a][3];
                }
            }
            __syncthreads();
            int grp = t >> 7, tt = t & 127;
            int s2 = grp ? nB : nA;
            if (s2 >= 0) {
                const float* h2c = &SH[grp ? H2BF : H2AF];
                float a = 0.f;
                for (int j = 0; j < 128; ++j)
                    a = fmaf(h2c[j], Mt[(size_t)j * 128 + tt], a);
                SH[s2 * 129 + tt] = a + t0g[tt];
            }
            __syncthreads();
        }
    }

    // ---- redo argmin for flagged lanes on exact zdot
    if (t < 64 && ((mask >> t) & 1ull)) {
#pragma unroll
        for (int g = 0; g < 4; ++g) {
            float best = 3.4e38f; int bi = g * 32;
#pragma unroll
            for (int k = 0; k < 32; ++k) {
                int c = g * 32 + k;
                float zd = SH[t * 129 + c];
                float nr = Pg[c * 128 + c];
                float a2 = 0.f;
#pragma unroll
                for (int gp = 0; gp < g; ++gp) a2 += Pg[cs[gp] * 128 + c];
                float dist = nr - 2.f * (zd - a2);
                if (dist < best) { best = dist; bi = c; }
            }
            cs[g] = bi;
        }
    }

    // ---- loss + codes from final choices
    if (t < 64) {
        float znorm = cg[0] + SH[PZF + t] + SH[PZF + 64 + t]
                    + SH[PZF + 128 + t] + SH[PZF + 192 + t];
        float S1 = 0.f, Sp = 0.f, msum = 0.f;
#pragma unroll
        for (int g = 0; g < 4; ++g) {
            int c = cs[g];
            float zd = SH[t * 129 + c];
            float nr = Pg[c * 128 + c];
            float a2 = 0.f;
#pragma unroll
            for (int gp = 0; gp < g; ++gp) a2 += Pg[cs[gp] * 128 + c];
            S1 += zd;
            Sp += nr + 2.f * a2;
            msum += (znorm - 2.f * S1 + Sp);
            codes_out[(size_t)(row0 + t) * 4 + g] = (float)(c - g * 32);
        }
#pragma unroll
        for (int off = 32; off; off >>= 1) msum += __shfl_down(msum, off);
        if (t == 0) atomicAdd(&loss_acc[0], msum);
    }
}

// ---------------------------------------------------------------------------
// K2: quant write (fp32) + cbW-gather L1 (fp32) + bf16-MFMA decoder L2/L3.
// (R9 verbatim)
// ---------------------------------------------------------------------------
__launch_bounds__(256, 4)
__global__ void k_dec(const float* __restrict__ codes_f, const float* __restrict__ cb,
                      const float* __restrict__ cbW, const float* __restrict__ b1,
                      const ushort_t* __restrict__ w2bf, const float* __restrict__ b2,
                      const ushort_t* __restrict__ w3bf, const float* __restrict__ b3,
                      float* __restrict__ quant_out, float* __restrict__ recon_out) {
    __shared__ __align__(16) unsigned char SHB[39424];
    int* cods = (int*)SHB;
    ushort_t* h2bf = (ushort_t*)SHB;
    ushort_t* h1bf = (ushort_t*)(SHB + 16384);
    float* Rl = (float*)(SHB + 16384);
    const int t = threadIdx.x;
    const int st = t & 15, ct = t >> 4;
    const int s0 = st * 4, o0 = ct * 8;
    const int row0 = blockIdx.x * 64;

    cods[t] = ((t & 3) << 5) + (int)codes_f[(size_t)row0 * 4 + t];
    float rb1[8];
#pragma unroll
    for (int i = 0; i < 8; ++i) rb1[i] = b1[o0 + i];
    __syncthreads();

    for (int i = 0; i < 32; ++i) {
        int idx4 = i * 256 + t;
        int s = idx4 >> 7, d4 = (idx4 & 127) * 4;
        const int* cp = &cods[s * 4];
        float4 a = *(const float4*)&cb[(size_t)cp[0] * 512 + d4];
        float4 b = *(const float4*)&cb[(size_t)cp[1] * 512 + d4];
        float4 c = *(const float4*)&cb[(size_t)cp[2] * 512 + d4];
        float4 d = *(const float4*)&cb[(size_t)cp[3] * 512 + d4];
        float4 vv;
        vv.x = a.x + b.x + c.x + d.x;
        vv.y = a.y + b.y + c.y + d.y;
        vv.z = a.z + b.z + c.z + d.z;
        vv.w = a.w + b.w + c.w + d.w;
        *(float4*)&quant_out[(size_t)(row0 + s) * 512 + d4] = vv;
    }

    {
        float accL[8][4];
#pragma unroll
        for (int b = 0; b < 4; ++b) {
            const int* cp = &cods[(s0 + b) * 4];
            float u[8] = {0, 0, 0, 0, 0, 0, 0, 0};
#pragma unroll
            for (int g = 0; g < 4; ++g) {
                const float* r = &cbW[(size_t)cp[g] * 128 + o0];
                float4 x0 = *(const float4*)r, x1 = *(const float4*)(r + 4);
                u[0] += x0.x; u[1] += x0.y; u[2] += x0.z; u[3] += x0.w;
                u[4] += x1.x; u[5] += x1.y; u[6] += x1.z; u[7] += x1.w;
            }
#pragma unroll
            for (int a = 0; a < 8; ++a) accL[a][b] = u[a];
        }
#pragma unroll
        for (int b = 0; b < 4; ++b) {
            int s = s0 + b;
            bf16x8 pk;
#pragma unroll
            for (int a = 0; a < 8; ++a)
                pk[a] = (short)f2bf(fmaxf(accL[a][b] + rb1[a], 0.f));
            *(bf16x8*)&h1bf[((s << 7) + o0) ^ ((s & 7) << 3)] = pk;
        }
    }
    __syncthreads();

    const int wv = t >> 6, lane = t & 63, lr = lane & 15, lg = lane >> 4;

    {
        f32x4 c2[2][4];
#pragma unroll
        for (int m = 0; m < 2; ++m)
#pragma unroll
            for (int n = 0; n < 4; ++n) c2[m][n] = (f32x4){0.f, 0.f, 0.f, 0.f};
#pragma unroll
        for (int kt = 0; kt < 4; ++kt) {
            bf16x8 af[2], bfr[4];
#pragma unroll
            for (int m = 0; m < 2; ++m)
                af[m] = *(const bf16x8*)&w2bf[(32 * wv + 16 * m + lr) * 128 + kt * 32 + lg * 8];
#pragma unroll
            for (int n = 0; n < 4; ++n) {
                int s = 16 * n + lr;
                bfr[n] = *(const bf16x8*)&h1bf[((s << 7) + kt * 32 + lg * 8) ^ ((s & 7) << 3)];
            }
#pragma unroll
            for (int m = 0; m < 2; ++m)
#pragma unroll
                for (int n = 0; n < 4; ++n)
                    c2[m][n] = MFMA16(af[m], bfr[n], c2[m][n]);
        }
        float rb[2][4];
#pragma unroll
        for (int m = 0; m < 2; ++m)
#pragma unroll
            for (int r = 0; r < 4; ++r) rb[m][r] = b2[32 * wv + 16 * m + lg * 4 + r];
#pragma unroll
        for (int m = 0; m < 2; ++m)
#pragma unroll
            for (int n = 0; n < 4; ++n) {
                int s = 16 * n + lr;
                s16x4 pk;
#pragma unroll
                for (int r = 0; r < 4; ++r)
                    pk[r] = (short)f2bf(fmaxf(c2[m][n][r] + rb[m][r], 0.f));
                int ob2 = 32 * wv + 16 * m + lg * 4;
                *(s16x4*)&h2bf[((s << 7) + ob2) ^ ((s & 7) << 3)] = pk;
            }
    }
    __syncthreads();

    {
        f32x4 c3[6];
#pragma unroll
        for (int m = 0; m < 6; ++m) c3[m] = (f32x4){0.f, 0.f, 0.f, 0.f};
        const int sB = 16 * wv + lr;
#pragma unroll
        for (int kt = 0; kt < 4; ++kt) {
            bf16x8 bfr = *(const bf16x8*)&h2bf[((sB << 7) + kt * 32 + lg * 8) ^ ((sB & 7) << 3)];
#pragma unroll
            for (int mt = 0; mt < 6; ++mt) {
                bf16x8 af = *(const bf16x8*)&w3bf[(16 * mt + lr) * 128 + kt * 32 + lg * 8];
                c3[mt] = MFMA16(af, bfr, c3[mt]);
            }
        }
#pragma unroll
        for (int mt = 0; mt < 6; ++mt)
#pragma unroll
            for (int r = 0; r < 4; ++r) {
                int o = 16 * mt + lg * 4 + r;
                if (o < 90) Rl[sB * 90 + o] = c3[mt][r] + b3[o];
            }
    }
    __syncthreads();

    {
        const float4* R4v = (const float4*)Rl;
        float4* G4 = (float4*)(recon_out + (size_t)row0 * 90);
#pragma unroll
        for (int it = 0; it < 6; ++it) {
            int i4 = it * 256 + t;
            if (i4 < 1440) G4[i4] = R4v[i4];
        }
    }
}

// ---------------------------------------------------------------------------
__global__ void k_loss(const float* __restrict__ acc, float* __restrict__ out) {
    out[0] = acc[0] * (1.0f / ((float)NSAMP * (float)DLAT));
}

extern "C" void kernel_launch(void* const* d_in, const int* in_sizes, int n_in,
                              void* d_out, int out_size, void* d_ws, size_t ws_size,
                              hipStream_t stream) {
    const float* state  = (const float*)d_in[0];
    const float* enc_w1 = (const float*)d_in[1];
    const float* enc_b1 = (const float*)d_in[2];
    const float* enc_w2 = (const float*)d_in[3];
    const float* enc_b2 = (const float*)d_in[4];
    const float* enc_w3 = (const float*)d_in[5];
    const float* enc_b3 = (const float*)d_in[6];
    const float* dec_w1 = (const float*)d_in[7];
    const float* dec_b1 = (const float*)d_in[8];
    const float* dec_w2 = (const float*)d_in[9];
    const float* dec_b2 = (const float*)d_in[10];
    const float* dec_w3 = (const float*)d_in[11];
    const float* dec_b3 = (const float*)d_in[12];
    const float* cb     = (const float*)d_in[13];

    float* out = (float*)d_out;
    float* P   = out;
    float* M   = out + 16384;
    ushort_t* Mhi = (ushort_t*)(out + 32768);
    ushort_t* Mlo = (ushort_t*)(out + 40960);
    float* t0  = out + 49152;
    float* v   = out + 49280;
    float* csc = out + 49408;
    float* ws = (float*)d_ws;
    float* loss_acc = ws;
    float* cbW = ws + 256;
    ushort_t* Qbf  = (ushort_t*)(ws + 16640);
    ushort_t* w2bf = (ushort_t*)(ws + 24832);
    ushort_t* w3bf = (ushort_t*)(ws + 33024);

    hipMemsetAsync(d_ws, 0, 16, stream);
    k_prep<<<448, 256, 0, stream>>>(cb, enc_w3, enc_b3, dec_w1, dec_w2, dec_w3,
                                    P, M, t0, v, csc, cbW, Qbf, w2bf, w3bf,
                                    Mhi, Mlo);
    k_encvq<<<NSAMP / 64, 256, 0, stream>>>(state, enc_w1, enc_b1, enc_w2, enc_b2,
                                            M, Qbf, Mhi, Mlo, t0, v, csc, P,
                                            out + OFF_CODE, loss_acc);
    k_dec<<<NSAMP / 64, 256, 0, stream>>>(out + OFF_CODE, cb, cbW,
                                          dec_b1, w2bf, dec_b2, w3bf, dec_b3,
                                          out, out + OFF_RECON);
    k_loss<<<1, 1, 0, stream>>>(loss_acc, out + OFF_LOSS);
}

// Round 13
// 348.401 us; speedup vs baseline: 1.7595x; 1.0807x over previous
//
#include <hip/hip_runtime.h>
#include <hip/hip_bf16.h>

#define NSAMP 131072
#define TA    90
#define HID   128
#define DLAT  512

// d_out layout (float elements): quant[N*512], code[N*4], recon[N*90], loss[1]
#define OFF_CODE  67108864ll
#define OFF_RECON (67108864ll + 524288ll)
#define OFF_LOSS  (67108864ll + 524288ll + 11796480ll)

// k_encvq LDS (floats): arenaA[8704] | Wl 2x[16][128]=4096 | PZ[4][64]=256
// arenaA: X fp32 [96][68] -> h1hi/h1lo (bf16 swz, floats 0..8191) -> h2hi/h2lo
// (same slots) -> zdot[64][129] (0..8255) | mask 8256 | H2A 8272 | H2B 8400
#define ACT_ST 68
#define WLF    8704
#define PZF    12800
#define SHF    13056
#define MSKF   8256
#define H2AF   8272
#define H2BF   8400
#define TAU    0.0625f

typedef __attribute__((ext_vector_type(8))) short bf16x8;
typedef __attribute__((ext_vector_type(4))) short s16x4;
typedef __attribute__((ext_vector_type(4))) float f32x4;
typedef unsigned short ushort_t;
#define MFMA16(a, b, c) __builtin_amdgcn_mfma_f32_16x16x32_bf16(a, b, c, 0, 0, 0)

__device__ __forceinline__ ushort_t f2bf(float f) {
    unsigned u = __float_as_uint(f);
    u = (u + 0x7FFF + ((u >> 16) & 1)) >> 16;     // RNE
    return (ushort_t)u;
}
__device__ __forceinline__ float bf2f(ushort_t u) {
    return __uint_as_float(((unsigned)u) << 16);
}

__device__ __forceinline__ float dot512(const float* __restrict__ a,
                                        const float* __restrict__ b) {
    float s = 0.f;
    for (int i = 0; i < 128; ++i) {
        float4 x = ((const float4*)a)[i], y = ((const float4*)b)[i];
        s += x.x * y.x + x.y * y.y + x.z * y.z + x.w * y.w;
    }
    return s;
}

// ---- R9-verbatim 8x4 tile FMA ----
__device__ __forceinline__ void fma_tile(float (&acc)[8][4],
                                         const float* __restrict__ wl,
                                         const float* __restrict__ al) {
    float4 av = *(const float4*)al;
    float4 w0 = *(const float4*)wl;
    float4 w1 = *(const float4*)(wl + 4);
    float aa[4] = {av.x, av.y, av.z, av.w};
    float ww[8] = {w0.x, w0.y, w0.z, w0.w, w1.x, w1.y, w1.z, w1.w};
#pragma unroll
    for (int a = 0; a < 8; ++a)
#pragma unroll
        for (int b = 0; b < 4; ++b) acc[a][b] = fmaf(ww[a], aa[b], acc[a][b]);
}

// ---- R9-verbatim double-buffered GEMM engine ----
__device__ __forceinline__ void gemm_dbuf(const float* __restrict__ w, int wstride,
                                          int inRows, int nch,
                                          const float* __restrict__ Act,
                                          float* __restrict__ Wl,
                                          float (&acc)[8][4],
                                          int t, int o0, int s0) {
    const int wr = t >> 4;
    const int wc = (t & 15) * 8;
    float4 c0, c1;
    {
        int r = wr < inRows ? wr : inRows - 1;
        const float* p = w + (size_t)r * wstride + wc;
        c0 = *(const float4*)p; c1 = *(const float4*)(p + 4);
    }
    *(float4*)&Wl[wr * 128 + wc] = c0;
    *(float4*)&Wl[wr * 128 + wc + 4] = c1;
    __syncthreads();
    for (int ch = 0; ch < nch; ++ch) {
        const float* Wc = &Wl[(ch & 1) * 2048];
        const bool more = (ch + 1 < nch);
        if (more) {
            int rr = (ch + 1) * 16 + wr;
            int r = rr < inRows ? rr : inRows - 1;
            const float* p = w + (size_t)r * wstride + wc;
            c0 = *(const float4*)p; c1 = *(const float4*)(p + 4);
        }
        const float* Ab = Act + (ch * 16) * ACT_ST + s0;
#pragma unroll
        for (int j = 0; j < 16; ++j)
            fma_tile(acc, &Wc[j * 128 + o0], Ab + j * ACT_ST);
        __syncthreads();
        if (more) {
            float* Wn = &Wl[((ch + 1) & 1) * 2048];
            *(float4*)&Wn[wr * 128 + wc] = c0;
            *(float4*)&Wn[wr * 128 + wc + 4] = c1;
            __syncthreads();
        }
    }
}

// ---------------------------------------------------------------------------
// K0: precompute tables. tbl6: Mhi/Mlo of M^T; tbl7: w2ehi/w2elo of enc_w2^T.
// ---------------------------------------------------------------------------
__global__ void k_prep(const float* __restrict__ cb, const float* __restrict__ w3,
                       const float* __restrict__ b3, const float* __restrict__ w1d,
                       const float* __restrict__ w2d, const float* __restrict__ w3d,
                       const float* __restrict__ w2e,
                       float* __restrict__ P, float* __restrict__ M,
                       float* __restrict__ t0, float* __restrict__ v,
                       float* __restrict__ csc, float* __restrict__ cbW,
                       ushort_t* __restrict__ Qbf, ushort_t* __restrict__ w2bf,
                       ushort_t* __restrict__ w3bf,
                       ushort_t* __restrict__ Mhibf, ushort_t* __restrict__ Mlobf,
                       ushort_t* __restrict__ w2ehi, ushort_t* __restrict__ w2elo) {
    int tbl = blockIdx.x >> 6;
    int gid = (blockIdx.x & 63) * 256 + threadIdx.x;   // 0..16383
    int i = gid >> 7, j = gid & 127;
    if (tbl == 0) {
        P[gid] = dot512(cb + (size_t)i * 512, cb + (size_t)j * 512);
        if (gid < 128) t0[gid] = dot512(cb + (size_t)gid * 512, b3);
        if (gid == 0) csc[0] = dot512(b3, b3);
    } else if (tbl == 1) {
        M[gid] = dot512(w3 + (size_t)i * 512, cb + (size_t)j * 512);
    } else if (tbl == 2) {
        Qbf[gid] = f2bf(dot512(w3 + (size_t)i * 512, w3 + (size_t)j * 512));
        if (gid < 128) v[gid] = dot512(w3 + (size_t)gid * 512, b3);
    } else if (tbl == 3) {
        float s = 0.f;
        for (int d = 0; d < 512; ++d) s = fmaf(cb[(size_t)i * 512 + d], w1d[d * 128 + j], s);
        cbW[gid] = s;
    } else if (tbl == 4) {
        w2bf[gid] = f2bf(w2d[j * 128 + i]);            // [o][j] = w2d[j][o]
    } else if (tbl == 5) {
        if (gid < 96 * 128)
            w3bf[gid] = (i < 90) ? f2bf(w3d[j * TA + i]) : (ushort_t)0;
    } else if (tbl == 6) {
        // i = code c, j = hidden. M^T split hi + lo.
        float d = dot512(w3 + (size_t)j * 512, cb + (size_t)i * 512);
        ushort_t hi = f2bf(d);
        Mhibf[gid] = hi;
        Mlobf[gid] = f2bf(d - bf2f(hi));
    } else {
        // tbl7: i = out o, j = hidden j. enc_w2^T split hi + lo.
        float d = w2e[j * 128 + i];
        ushort_t hi = f2bf(d);
        w2ehi[gid] = hi;
        w2elo[gid] = f2bf(d - bf2f(hi));
    }
}

// ---------------------------------------------------------------------------
// K1: encoder (L1 fp32, L2 split-bf16 MFMA) + split-bf16 scoring + Q-loss
//     + argmin with pair-parallel exact full-chain fallback (h1 in regs).
// ---------------------------------------------------------------------------
__launch_bounds__(256, 3)
__global__ void k_encvq(const float* __restrict__ X,
                        const float* __restrict__ w1, const float* __restrict__ b1,
                        const float* __restrict__ w2, const float* __restrict__ b2,
                        const ushort_t* __restrict__ w2ehi, const ushort_t* __restrict__ w2elo,
                        const float* __restrict__ Mt, const ushort_t* __restrict__ Qbf,
                        const ushort_t* __restrict__ Mhi, const ushort_t* __restrict__ Mlo,
                        const float* __restrict__ t0g, const float* __restrict__ vg,
                        const float* __restrict__ cg, const float* __restrict__ Pg,
                        float* __restrict__ codes_out, float* __restrict__ loss_acc) {
    __shared__ __align__(16) float SH[SHF];
    float* Act = SH;
    float* Wl  = SH + WLF;
    ushort_t* hAhi = (ushort_t*)SH;            // h1 then h2 splits: floats 0..4095
    ushort_t* hAlo = (ushort_t*)(SH + 4096);   // floats 4096..8191
    const int t = threadIdx.x;
    const int st = t & 15, ct = t >> 4;
    const int s0 = st * 4, o0 = ct * 8;
    const int row0 = blockIdx.x * 64;

    float rb1[8];
#pragma unroll
    for (int i = 0; i < 8; ++i) rb1[i] = b1[o0 + i];

    // stage X^T (rows 90..95 zero-padded) — R9 verbatim
    for (int it = 0; it < 24; ++it) {
        int idx = it * 256 + t;
        int j = idx >> 6, s = idx & 63;
        Act[j * ACT_ST + s] = (j < 90) ? X[(size_t)(row0 + s) * TA + j] : 0.f;
    }

    float acc[8][4];
#pragma unroll
    for (int a = 0; a < 8; ++a)
#pragma unroll
        for (int b = 0; b < 4; ++b) acc[a][b] = 0.f;
    gemm_dbuf(w1, HID, 90, 6, Act, Wl, acc, t, o0, s0);
    // (trailing barrier: all X reads done -> arenaA reusable)

    // L1 epilogue: h1 = relu(acc+b1) kept EXACT in acc; splits -> hAhi/hAlo
    {
#pragma unroll
        for (int b = 0; b < 4; ++b) {
            int s = s0 + b;
            bf16x8 pkh, pkl;
#pragma unroll
            for (int a = 0; a < 8; ++a) {
                float hv = fmaxf(acc[a][b] + rb1[a], 0.f);
                acc[a][b] = hv;                       // exact h1 stays in regs
                ushort_t hi = f2bf(hv);
                pkh[a] = (short)hi;
                pkl[a] = (short)f2bf(hv - bf2f(hi));
            }
            int adr = ((s << 7) + o0) ^ ((s & 7) << 3);
            *(bf16x8*)&hAhi[adr] = pkh;
            *(bf16x8*)&hAlo[adr] = pkl;
        }
    }
    __syncthreads();

    const int wv = t >> 6, lane = t & 63, lr = lane & 15, lg = lane >> 4;

    // ---- L2 via split-bf16 MFMA: h2 = relu(w2e·h1 + b2), 3-term
    {
        f32x4 c2[2][4];
#pragma unroll
        for (int m = 0; m < 2; ++m)
#pragma unroll
            for (int n = 0; n < 4; ++n) c2[m][n] = (f32x4){0.f, 0.f, 0.f, 0.f};
#pragma unroll
        for (int kt = 0; kt < 4; ++kt) {
            bf16x8 ah[2], al[2], bhi[4], blo[4];
#pragma unroll
            for (int m = 0; m < 2; ++m) {
                int arow = (32 * wv + 16 * m + lr) * 128 + kt * 32 + lg * 8;
                ah[m] = *(const bf16x8*)&w2ehi[arow];
                al[m] = *(const bf16x8*)&w2elo[arow];
            }
#pragma unroll
            for (int n = 0; n < 4; ++n) {
                int s = 16 * n + lr;
                int adr = ((s << 7) + kt * 32 + lg * 8) ^ ((s & 7) << 3);
                bhi[n] = *(const bf16x8*)&hAhi[adr];
                blo[n] = *(const bf16x8*)&hAlo[adr];
            }
#pragma unroll
            for (int m = 0; m < 2; ++m)
#pragma unroll
                for (int n = 0; n < 4; ++n) {
                    c2[m][n] = MFMA16(ah[m], bhi[n], c2[m][n]);
                    c2[m][n] = MFMA16(ah[m], blo[n], c2[m][n]);
                    c2[m][n] = MFMA16(al[m], bhi[n], c2[m][n]);
                }
        }
        __syncthreads();   // all h1-split reads done -> slots reusable for h2
        float rbf[2][4];
#pragma unroll
        for (int m = 0; m < 2; ++m)
#pragma unroll
            for (int r = 0; r < 4; ++r) rbf[m][r] = b2[32 * wv + 16 * m + lg * 4 + r];
#pragma unroll
        for (int m = 0; m < 2; ++m)
#pragma unroll
            for (int n = 0; n < 4; ++n) {
                int s = 16 * n + lr;
                s16x4 ph, pl;
#pragma unroll
                for (int r = 0; r < 4; ++r) {
                    float hv = fmaxf(c2[m][n][r] + rbf[m][r], 0.f);
                    ushort_t hi = f2bf(hv);
                    ph[r] = (short)hi;
                    pl[r] = (short)f2bf(hv - bf2f(hi));
                }
                int ob2 = 32 * wv + 16 * m + lg * 4;
                int adr = ((s << 7) + ob2) ^ ((s & 7) << 3);
                *(s16x4*)&hAhi[adr] = ph;
                *(s16x4*)&hAlo[adr] = pl;
            }
    }
    __syncthreads();

    // ---- MFMA phase (R12-verbatim): qc = Q*h2hi; sc = Mhi*hi + Mhi*lo + Mlo*hi
    f32x4 sc[2][4];
    {
        f32x4 qc[2][4];
#pragma unroll
        for (int m = 0; m < 2; ++m)
#pragma unroll
            for (int n = 0; n < 4; ++n) {
                qc[m][n] = (f32x4){0.f, 0.f, 0.f, 0.f};
                sc[m][n] = (f32x4){0.f, 0.f, 0.f, 0.f};
            }
#pragma unroll
        for (int kt = 0; kt < 4; ++kt) {
            bf16x8 aq[2], amh[2], aml[2], bhi[4], blo[4];
#pragma unroll
            for (int m = 0; m < 2; ++m) {
                int arow = (32 * wv + 16 * m + lr) * 128 + kt * 32 + lg * 8;
                aq[m]  = *(const bf16x8*)&Qbf[arow];
                amh[m] = *(const bf16x8*)&Mhi[arow];
                aml[m] = *(const bf16x8*)&Mlo[arow];
            }
#pragma unroll
            for (int n = 0; n < 4; ++n) {
                int s = 16 * n + lr;
                int adr = ((s << 7) + kt * 32 + lg * 8) ^ ((s & 7) << 3);
                bhi[n] = *(const bf16x8*)&hAhi[adr];
                blo[n] = *(const bf16x8*)&hAlo[adr];
            }
#pragma unroll
            for (int m = 0; m < 2; ++m)
#pragma unroll
                for (int n = 0; n < 4; ++n) {
                    qc[m][n] = MFMA16(aq[m], bhi[n], qc[m][n]);
                    sc[m][n] = MFMA16(amh[m], bhi[n], sc[m][n]);
                    sc[m][n] = MFMA16(amh[m], blo[n], sc[m][n]);
                    sc[m][n] = MFMA16(aml[m], bhi[n], sc[m][n]);
                }
        }
        float v2[2][4];
#pragma unroll
        for (int m = 0; m < 2; ++m)
#pragma unroll
            for (int r = 0; r < 4; ++r) v2[m][r] = 2.f * vg[32 * wv + 16 * m + lg * 4 + r];
#pragma unroll
        for (int n = 0; n < 4; ++n) {
            int s = 16 * n + lr;
            float p = 0.f;
#pragma unroll
            for (int m = 0; m < 2; ++m)
#pragma unroll
                for (int r = 0; r < 4; ++r) {
                    int o = 32 * wv + 16 * m + lg * 4 + r;
                    int adr = ((s << 7) + o) ^ ((s & 7) << 3);
                    float hv = bf2f(hAhi[adr]) + bf2f(hAlo[adr]);
                    p = fmaf(qc[m][n][r] + v2[m][r], hv, p);
                }
            p += __shfl_xor(p, 16);
            p += __shfl_xor(p, 32);
            if (lg == 0) SH[PZF + wv * 64 + s] = p;
        }
    }
    __syncthreads();   // all h2 reads done -> arenaA reusable for zdot

    // dump S (+t0) as zdot, stride 129
#pragma unroll
    for (int m = 0; m < 2; ++m)
#pragma unroll
        for (int n = 0; n < 4; ++n) {
            int s = 16 * n + lr;
#pragma unroll
            for (int r = 0; r < 4; ++r) {
                int o = 32 * wv + 16 * m + lg * 4 + r;
                SH[s * 129 + o] = sc[m][n][r] + t0g[o];
            }
        }
    __syncthreads();

    // ---- fast argmin chain with margin tracking; wave-0 ballot -> mask
    int cs[4];
    if (t < 64) {
        float marg = 3.4e38f;
#pragma unroll
        for (int g = 0; g < 4; ++g) {
            float best = 3.4e38f, best2 = 3.4e38f; int bi = g * 32;
#pragma unroll
            for (int k = 0; k < 32; ++k) {
                int c = g * 32 + k;
                float zd = SH[t * 129 + c];
                float nr = Pg[c * 128 + c];
                float a2 = 0.f;
#pragma unroll
                for (int gp = 0; gp < g; ++gp) a2 += Pg[cs[gp] * 128 + c];
                float dist = nr - 2.f * (zd - a2);
                if (dist < best) { best2 = best; best = dist; bi = c; }
                else if (dist < best2) { best2 = dist; }
            }
            cs[g] = bi;
            float m2 = best2 - best;
            marg = (m2 < marg) ? m2 : marg;
        }
        unsigned long long mk = __ballot(marg < TAU);
        if (t == 0) *(unsigned long long*)&SH[MSKF] = mk;
    }
    __syncthreads();

    const unsigned long long mask = *(const unsigned long long*)&SH[MSKF];

    // ---- exact full-chain fallback (h1 from regs; h2,zdot R9-chain-identical)
    {
        unsigned long long mk = mask;
        while (mk) {
            int nA = (int)__ffsll((long long)mk) - 1; mk &= mk - 1;
            int nB = -1;
            if (mk) { nB = (int)__ffsll((long long)mk) - 1; mk &= mk - 1; }
            // dump exact h1 columns (R12 pattern)
            if ((t & 15) == (nA >> 2)) {
                int bb = nA & 3;
                if (bb == 0) {
#pragma unroll
                    for (int a = 0; a < 8; ++a) SH[H2AF + o0 + a] = acc[a][0];
                } else if (bb == 1) {
#pragma unroll
                    for (int a = 0; a < 8; ++a) SH[H2AF + o0 + a] = acc[a][1];
                } else if (bb == 2) {
#pragma unroll
                    for (int a = 0; a < 8; ++a) SH[H2AF + o0 + a] = acc[a][2];
                } else {
#pragma unroll
                    for (int a = 0; a < 8; ++a) SH[H2AF + o0 + a] = acc[a][3];
                }
            }
            if (nB >= 0 && (t & 15) == (nB >> 2)) {
                int bb = nB & 3;
                if (bb == 0) {
#pragma unroll
                    for (int a = 0; a < 8; ++a) SH[H2BF + o0 + a] = acc[a][0];
                } else if (bb == 1) {
#pragma unroll
                    for (int a = 0; a < 8; ++a) SH[H2BF + o0 + a] = acc[a][1];
                } else if (bb == 2) {
#pragma unroll
                    for (int a = 0; a < 8; ++a) SH[H2BF + o0 + a] = acc[a][2];
                } else {
#pragma unroll
                    for (int a = 0; a < 8; ++a) SH[H2BF + o0 + a] = acc[a][3];
                }
            }
            __syncthreads();
            int grp = t >> 7, tt = t & 127;
            int s2 = grp ? nB : nA;
            // exact h2 (ascending-j fmaf + b2 + relu == gemm_dbuf chain)
            float hv2 = 0.f;
            if (s2 >= 0) {
                const float* h1c = &SH[grp ? H2BF : H2AF];
                for (int j = 0; j < 128; ++j)
                    hv2 = fmaf(h1c[j], w2[(size_t)j * 128 + tt], hv2);
                hv2 = fmaxf(hv2 + b2[tt], 0.f);
            }
            __syncthreads();   // all h1 reads done
            if (s2 >= 0) SH[(grp ? H2BF : H2AF) + tt] = hv2;
            __syncthreads();
            if (s2 >= 0) {
                const float* h2c = &SH[grp ? H2BF : H2AF];
                float a = 0.f;
                for (int j = 0; j < 128; ++j)
                    a = fmaf(h2c[j], Mt[(size_t)j * 128 + tt], a);
                SH[s2 * 129 + tt] = a + t0g[tt];
            }
            __syncthreads();
        }
    }

    // ---- redo argmin for flagged lanes on exact zdot
    if (t < 64 && ((mask >> t) & 1ull)) {
#pragma unroll
        for (int g = 0; g < 4; ++g) {
            float best = 3.4e38f; int bi = g * 32;
#pragma unroll
            for (int k = 0; k < 32; ++k) {
                int c = g * 32 + k;
                float zd = SH[t * 129 + c];
                float nr = Pg[c * 128 + c];
                float a2 = 0.f;
#pragma unroll
                for (int gp = 0; gp < g; ++gp) a2 += Pg[cs[gp] * 128 + c];
                float dist = nr - 2.f * (zd - a2);
                if (dist < best) { best = dist; bi = c; }
            }
            cs[g] = bi;
        }
    }

    // ---- loss + codes from final choices
    if (t < 64) {
        float znorm = cg[0] + SH[PZF + t] + SH[PZF + 64 + t]
                    + SH[PZF + 128 + t] + SH[PZF + 192 + t];
        float S1 = 0.f, Sp = 0.f, msum = 0.f;
#pragma unroll
        for (int g = 0; g < 4; ++g) {
            int c = cs[g];
            float zd = SH[t * 129 + c];
            float nr = Pg[c * 128 + c];
            float a2 = 0.f;
#pragma unroll
            for (int gp = 0; gp < g; ++gp) a2 += Pg[cs[gp] * 128 + c];
            S1 += zd;
            Sp += nr + 2.f * a2;
            msum += (znorm - 2.f * S1 + Sp);
            codes_out[(size_t)(row0 + t) * 4 + g] = (float)(c - g * 32);
        }
#pragma unroll
        for (int off = 32; off; off >>= 1) msum += __shfl_down(msum, off);
        if (t == 0) atomicAdd(&loss_acc[0], msum);
    }
}

// ---------------------------------------------------------------------------
// K2: quant write (fp32) + cbW-gather L1 (fp32) + bf16-MFMA decoder L2/L3.
// (R9 verbatim)
// ---------------------------------------------------------------------------
__launch_bounds__(256, 4)
__global__ void k_dec(const float* __restrict__ codes_f, const float* __restrict__ cb,
                      const float* __restrict__ cbW, const float* __restrict__ b1,
                      const ushort_t* __restrict__ w2bf, const float* __restrict__ b2,
                      const ushort_t* __restrict__ w3bf, const float* __restrict__ b3,
                      float* __restrict__ quant_out, float* __restrict__ recon_out) {
    __shared__ __align__(16) unsigned char SHB[39424];
    int* cods = (int*)SHB;
    ushort_t* h2bf = (ushort_t*)SHB;
    ushort_t* h1bf = (ushort_t*)(SHB + 16384);
    float* Rl = (float*)(SHB + 16384);
    const int t = threadIdx.x;
    const int st = t & 15, ct = t >> 4;
    const int s0 = st * 4, o0 = ct * 8;
    const int row0 = blockIdx.x * 64;

    cods[t] = ((t & 3) << 5) + (int)codes_f[(size_t)row0 * 4 + t];
    float rb1[8];
#pragma unroll
    for (int i = 0; i < 8; ++i) rb1[i] = b1[o0 + i];
    __syncthreads();

    for (int i = 0; i < 32; ++i) {
        int idx4 = i * 256 + t;
        int s = idx4 >> 7, d4 = (idx4 & 127) * 4;
        const int* cp = &cods[s * 4];
        float4 a = *(const float4*)&cb[(size_t)cp[0] * 512 + d4];
        float4 b = *(const float4*)&cb[(size_t)cp[1] * 512 + d4];
        float4 c = *(const float4*)&cb[(size_t)cp[2] * 512 + d4];
        float4 d = *(const float4*)&cb[(size_t)cp[3] * 512 + d4];
        float4 vv;
        vv.x = a.x + b.x + c.x + d.x;
        vv.y = a.y + b.y + c.y + d.y;
        vv.z = a.z + b.z + c.z + d.z;
        vv.w = a.w + b.w + c.w + d.w;
        *(float4*)&quant_out[(size_t)(row0 + s) * 512 + d4] = vv;
    }

    {
        float accL[8][4];
#pragma unroll
        for (int b = 0; b < 4; ++b) {
            const int* cp = &cods[(s0 + b) * 4];
            float u[8] = {0, 0, 0, 0, 0, 0, 0, 0};
#pragma unroll
            for (int g = 0; g < 4; ++g) {
                const float* r = &cbW[(size_t)cp[g] * 128 + o0];
                float4 x0 = *(const float4*)r, x1 = *(const float4*)(r + 4);
                u[0] += x0.x; u[1] += x0.y; u[2] += x0.z; u[3] += x0.w;
                u[4] += x1.x; u[5] += x1.y; u[6] += x1.z; u[7] += x1.w;
            }
#pragma unroll
            for (int a = 0; a < 8; ++a) accL[a][b] = u[a];
        }
#pragma unroll
        for (int b = 0; b < 4; ++b) {
            int s = s0 + b;
            bf16x8 pk;
#pragma unroll
            for (int a = 0; a < 8; ++a)
                pk[a] = (short)f2bf(fmaxf(accL[a][b] + rb1[a], 0.f));
            *(bf16x8*)&h1bf[((s << 7) + o0) ^ ((s & 7) << 3)] = pk;
        }
    }
    __syncthreads();

    const int wv = t >> 6, lane = t & 63, lr = lane & 15, lg = lane >> 4;

    {
        f32x4 c2[2][4];
#pragma unroll
        for (int m = 0; m < 2; ++m)
#pragma unroll
            for (int n = 0; n < 4; ++n) c2[m][n] = (f32x4){0.f, 0.f, 0.f, 0.f};
#pragma unroll
        for (int kt = 0; kt < 4; ++kt) {
            bf16x8 af[2], bfr[4];
#pragma unroll
            for (int m = 0; m < 2; ++m)
                af[m] = *(const bf16x8*)&w2bf[(32 * wv + 16 * m + lr) * 128 + kt * 32 + lg * 8];
#pragma unroll
            for (int n = 0; n < 4; ++n) {
                int s = 16 * n + lr;
                bfr[n] = *(const bf16x8*)&h1bf[((s << 7) + kt * 32 + lg * 8) ^ ((s & 7) << 3)];
            }
#pragma unroll
            for (int m = 0; m < 2; ++m)
#pragma unroll
                for (int n = 0; n < 4; ++n)
                    c2[m][n] = MFMA16(af[m], bfr[n], c2[m][n]);
        }
        float rb[2][4];
#pragma unroll
        for (int m = 0; m < 2; ++m)
#pragma unroll
            for (int r = 0; r < 4; ++r) rb[m][r] = b2[32 * wv + 16 * m + lg * 4 + r];
#pragma unroll
        for (int m = 0; m < 2; ++m)
#pragma unroll
            for (int n = 0; n < 4; ++n) {
                int s = 16 * n + lr;
                s16x4 pk;
#pragma unroll
                for (int r = 0; r < 4; ++r)
                    pk[r] = (short)f2bf(fmaxf(c2[m][n][r] + rb[m][r], 0.f));
                int ob2 = 32 * wv + 16 * m + lg * 4;
                *(s16x4*)&h2bf[((s << 7) + ob2) ^ ((s & 7) << 3)] = pk;
            }
    }
    __syncthreads();

    {
        f32x4 c3[6];
#pragma unroll
        for (int m = 0; m < 6; ++m) c3[m] = (f32x4){0.f, 0.f, 0.f, 0.f};
        const int sB = 16 * wv + lr;
#pragma unroll
        for (int kt = 0; kt < 4; ++kt) {
            bf16x8 bfr = *(const bf16x8*)&h2bf[((sB << 7) + kt * 32 + lg * 8) ^ ((sB & 7) << 3)];
#pragma unroll
            for (int mt = 0; mt < 6; ++mt) {
                bf16x8 af = *(const bf16x8*)&w3bf[(16 * mt + lr) * 128 + kt * 32 + lg * 8];
                c3[mt] = MFMA16(af, bfr, c3[mt]);
            }
        }
#pragma unroll
        for (int mt = 0; mt < 6; ++mt)
#pragma unroll
            for (int r = 0; r < 4; ++r) {
                int o = 16 * mt + lg * 4 + r;
                if (o < 90) Rl[sB * 90 + o] = c3[mt][r] + b3[o];
            }
    }
    __syncthreads();

    {
        const float4* R4v = (const float4*)Rl;
        float4* G4 = (float4*)(recon_out + (size_t)row0 * 90);
#pragma unroll
        for (int it = 0; it < 6; ++it) {
            int i4 = it * 256 + t;
            if (i4 < 1440) G4[i4] = R4v[i4];
        }
    }
}

// ---------------------------------------------------------------------------
__global__ void k_loss(const float* __restrict__ acc, float* __restrict__ out) {
    out[0] = acc[0] * (1.0f / ((float)NSAMP * (float)DLAT));
}

extern "C" void kernel_launch(void* const* d_in, const int* in_sizes, int n_in,
                              void* d_out, int out_size, void* d_ws, size_t ws_size,
                              hipStream_t stream) {
    const float* state  = (const float*)d_in[0];
    const float* enc_w1 = (const float*)d_in[1];
    const float* enc_b1 = (const float*)d_in[2];
    const float* enc_w2 = (const float*)d_in[3];
    const float* enc_b2 = (const float*)d_in[4];
    const float* enc_w3 = (const float*)d_in[5];
    const float* enc_b3 = (const float*)d_in[6];
    const float* dec_w1 = (const float*)d_in[7];
    const float* dec_b1 = (const float*)d_in[8];
    const float* dec_w2 = (const float*)d_in[9];
    const float* dec_b2 = (const float*)d_in[10];
    const float* dec_w3 = (const float*)d_in[11];
    const float* dec_b3 = (const float*)d_in[12];
    const float* cb     = (const float*)d_in[13];

    float* out = (float*)d_out;
    float* P   = out;
    float* M   = out + 16384;
    ushort_t* Mhi = (ushort_t*)(out + 32768);
    ushort_t* Mlo = (ushort_t*)(out + 40960);
    float* t0  = out + 49152;
    float* v   = out + 49280;
    float* csc = out + 49408;
    ushort_t* w2ehi = (ushort_t*)(out + 49664);
    ushort_t* w2elo = (ushort_t*)(out + 57856);
    float* ws = (float*)d_ws;
    float* loss_acc = ws;
    float* cbW = ws + 256;
    ushort_t* Qbf  = (ushort_t*)(ws + 16640);
    ushort_t* w2bf = (ushort_t*)(ws + 24832);
    ushort_t* w3bf = (ushort_t*)(ws + 33024);

    hipMemsetAsync(d_ws, 0, 16, stream);
    k_prep<<<512, 256, 0, stream>>>(cb, enc_w3, enc_b3, dec_w1, dec_w2, dec_w3,
                                    enc_w2,
                                    P, M, t0, v, csc, cbW, Qbf, w2bf, w3bf,
                                    Mhi, Mlo, w2ehi, w2elo);
    k_encvq<<<NSAMP / 64, 256, 0, stream>>>(state, enc_w1, enc_b1, enc_w2, enc_b2,
                                            w2ehi, w2elo,
                                            M, Qbf, Mhi, Mlo, t0, v, csc, P,
                                            out + OFF_CODE, loss_acc);
    k_dec<<<NSAMP / 64, 256, 0, stream>>>(out + OFF_CODE, cb, cbW,
                                          dec_b1, w2bf, dec_b2, w3bf, dec_b3,
                                          out, out + OFF_RECON);
    k_loss<<<1, 1, 0, stream>>>(loss_acc, out + OFF_LOSS);
}